// Round 13
// baseline (164.509 us; speedup 1.0000x reference)
//
#include <hip/hip_runtime.h>
#include <stdint.h>

#define NTOK 8192
#define DIM  1024
#define NE   8
#define NPAIR 28
#define OUTD 4096
#define MAXT16 539   // >= sum_p ceil(cnt_p/16): 512 + 27 worst case

typedef __attribute__((ext_vector_type(8))) short bf16x8;
typedef __attribute__((ext_vector_type(4))) float f32x4;

static __device__ __forceinline__ unsigned short f2bf(float f) {
    uint32_t u = __float_as_uint(f);
    u += 0x7fffu + ((u >> 16) & 1u);     // RNE
    return (unsigned short)(u >> 16);
}

// ---- K1: fused prep: gate (bid<2048) | W1 repack (2048..2079) | W2 repack (2080..2207) ----
// w1m[e][j][k][i]  i contiguous : 524288 elems
// w2m[e][k][l][j]  j contiguous : 1048576 elems
__global__ __launch_bounds__(256) void k_prep(const float* __restrict__ x,
                                              const float* __restrict__ Wg,
                                              const float* __restrict__ W1,
                                              const float* __restrict__ W2,
                                              unsigned short* __restrict__ w1m,
                                              unsigned short* __restrict__ w2m,
                                              int* __restrict__ pairCnt,
                                              int* __restrict__ bucket,
                                              float* __restrict__ wgt) {
    __shared__ float smemf[8256];                   // 33 KB union
    int bid = blockIdx.x;
    int tid = threadIdx.x;

    if (bid < 2048) {
        // ================= gate =================
        float* sWg = smemf;                         // [8][1024]
        #pragma unroll
        for (int u = 0; u < 8; ++u) {
            int idx = u * 1024 + tid * 4;
            *(float4*)&sWg[idx] = *(const float4*)&Wg[idx];
        }
        __syncthreads();
        int w = tid >> 6, lane = tid & 63;
        int tok = bid * 4 + w;
        float acc[NE];
        #pragma unroll
        for (int e = 0; e < NE; ++e) acc[e] = 0.f;
        const float* xr = x + (size_t)tok * DIM;
        #pragma unroll
        for (int c = 0; c < 4; ++c) {
            float4 xv = *(const float4*)&xr[c * 256 + lane * 4];
            #pragma unroll
            for (int e = 0; e < NE; ++e) {
                float4 wv = *(const float4*)&sWg[e * 1024 + c * 256 + lane * 4];
                acc[e] += xv.x * wv.x + xv.y * wv.y + xv.z * wv.z + xv.w * wv.w;
            }
        }
        #pragma unroll
        for (int e = 0; e < NE; ++e)
            #pragma unroll
            for (int off = 32; off > 0; off >>= 1)
                acc[e] += __shfl_xor(acc[e], off, 64);
        if (lane == 0) {
            int i1 = 0; float v1 = acc[0];
            for (int e = 1; e < NE; ++e) if (acc[e] > v1) { v1 = acc[e]; i1 = e; }
            int i2 = -1; float v2 = -3.4e38f;
            for (int e = 0; e < NE; ++e) { if (e == i1) continue; if (acc[e] > v2) { v2 = acc[e]; i2 = e; } }
            float ex = expf(v2 - v1);
            float s  = 1.f / (1.f + ex);
            float w1v = s + 1e-6f;
            float w2v = ex * s + 1e-6f;
            int ea = min(i1, i2), eb = max(i1, i2);
            float wa = (i1 < i2) ? w1v : w2v;
            float wb = (i1 < i2) ? w2v : w1v;
            wgt[tok * 2 + 0] = wa;
            wgt[tok * 2 + 1] = wb;
            int pid = ea * 7 - (ea * (ea - 1)) / 2 + (eb - ea - 1);
            int pos = atomicAdd(&pairCnt[pid], 1);
            bucket[pid * NTOK + pos] = tok;
        }
    } else if (bid < 2080) {
        // ================= W1 repack: block j, coalesced both sides =================
        int j = bid - 2048;
        unsigned short* lds = (unsigned short*)smemf;   // [32][514] bf16, pad->bank-free
        const float* src = W1 + (size_t)j * 16384;
        int f0 = tid * 64;
        #pragma unroll
        for (int c = 0; c < 16; ++c) {
            int f = f0 + c * 4;
            float4 v = *(const float4*)&src[f];
            int i = f >> 9, rem = f & 511;
            unsigned short* d = lds + i * 514 + rem;
            d[0] = f2bf(v.x); d[1] = f2bf(v.y); d[2] = f2bf(v.z); d[3] = f2bf(v.w);
        }
        __syncthreads();
        int e = tid >> 5, kp = tid & 31;
        #pragma unroll
        for (int dk = 0; dk < 2; ++dk) {
            int k = kp * 2 + dk;
            uint32_t q[16];
            #pragma unroll
            for (int c = 0; c < 16; ++c) {
                uint32_t lo = lds[(2 * c) * 514 + k * 8 + e];
                uint32_t hi = lds[(2 * c + 1) * 514 + k * 8 + e];
                q[c] = lo | (hi << 16);
            }
            unsigned short* dst = w1m + (((size_t)e * 32 + j) * 64 + k) * 32;
            #pragma unroll
            for (int c = 0; c < 4; ++c) {
                uint4 u; u.x = q[c*4]; u.y = q[c*4+1]; u.z = q[c*4+2]; u.w = q[c*4+3];
                *(uint4*)(dst + c * 8) = u;
            }
        }
    } else {
        // ================= W2 repack: block = 4 (e,k) pairs =================
        int ek4 = bid - 2080;                       // 0..127
        unsigned short* lds = (unsigned short*)smemf;   // [4][32*66] bf16
        int sub = tid >> 6, l6 = tid & 63;
        const float* s2 = W2 + (size_t)ek4 * 8192 + sub * 2048 + l6 * 32;
        #pragma unroll
        for (int c = 0; c < 32; c += 4) {
            float4 v = *(const float4*)&s2[c];
            int f = l6 * 32 + c;
            int j = f >> 6, l = f & 63;
            unsigned short* d = lds + sub * 2112 + j * 66 + l;
            d[0] = f2bf(v.x); d[1] = f2bf(v.y); d[2] = f2bf(v.z); d[3] = f2bf(v.w);
        }
        __syncthreads();
        uint32_t q[16];
        #pragma unroll
        for (int c = 0; c < 16; ++c) {
            uint32_t lo = lds[sub * 2112 + (2 * c) * 66 + l6];
            uint32_t hi = lds[sub * 2112 + (2 * c + 1) * 66 + l6];
            q[c] = lo | (hi << 16);
        }
        unsigned short* dst = w2m + ((size_t)ek4 * 4 + sub) * 2048 + l6 * 32;
        #pragma unroll
        for (int c = 0; c < 4; ++c) {
            uint4 u; u.x = q[c*4]; u.y = q[c*4+1]; u.z = q[c*4+2]; u.w = q[c*4+3];
            *(uint4*)(dst + c * 8) = u;
        }
    }
}

// ---- K2: slot -> token map + 16-token tile descriptors ----
__global__ __launch_bounds__(256) void k_slots(const int* __restrict__ pairCnt,
                                               const int* __restrict__ bucket,
                                               int* __restrict__ tokmap,
                                               int4* __restrict__ tileDesc) {
    int s = blockIdx.x * 256 + threadIdx.x;
    {
        int off = 0;
        for (int p = 0; p < NPAIR; ++p) {
            int c = pairCnt[p];
            if (s < off + c) { tokmap[s] = bucket[p * NTOK + (s - off)]; break; }
            off += c;
        }
    }
    if (s < MAXT16) {
        int4 d; d.x = -1; d.y = 0; d.z = 0; d.w = 0;
        int toff = 0, soff = 0;
        for (int q = 0; q < NPAIR; ++q) {
            int c = pairCnt[q];
            int nt = (c + 15) >> 4;
            if (d.x < 0 && s < toff + nt) {
                int lt = s - toff;
                d.x = q;
                d.y = soff + lt * 16;
                d.z = min(16, c - lt * 16);
            }
            toff += nt; soff += c;
        }
        tileDesc[s] = d;
    }
}

// ---- K3: gather x -> xg3[j][slot][i] bf16 (64-B rows), LDS transpose ----
__global__ __launch_bounds__(256) void k_xg3(const float* __restrict__ x,
                                             const int* __restrict__ tokmap,
                                             unsigned short* __restrict__ xg3) {
    __shared__ float tile[8][1056];                 // pad +1 per 32
    int s0 = blockIdx.x * 8;
    int tid = threadIdx.x;
    int r = tid >> 5, c = tid & 31;
    int tok = tokmap[s0 + r];
    const float* xr = x + (size_t)tok * DIM;
    #pragma unroll
    for (int u = 0; u < 8; ++u) {
        int d = u * 128 + c * 4;
        float4 v = *(const float4*)&xr[d];
        int d2 = d + (d >> 5);
        tile[r][d2 + 0] = v.x; tile[r][d2 + 1] = v.y;
        tile[r][d2 + 2] = v.z; tile[r][d2 + 3] = v.w;
    }
    __syncthreads();
    int sl = tid >> 5, j = tid & 31;
    float v[32];
    #pragma unroll
    for (int i = 0; i < 32; ++i) v[i] = tile[sl][i * 33 + j];
    unsigned short* orow = xg3 + ((size_t)j * NTOK + s0 + sl) * 32;
    #pragma unroll
    for (int ic = 0; ic < 4; ++ic) {
        uint4 pk;
        pk.x = (uint32_t)f2bf(v[ic * 8 + 0]) | ((uint32_t)f2bf(v[ic * 8 + 1]) << 16);
        pk.y = (uint32_t)f2bf(v[ic * 8 + 2]) | ((uint32_t)f2bf(v[ic * 8 + 3]) << 16);
        pk.z = (uint32_t)f2bf(v[ic * 8 + 4]) | ((uint32_t)f2bf(v[ic * 8 + 5]) << 16);
        pk.w = (uint32_t)f2bf(v[ic * 8 + 6]) | ((uint32_t)f2bf(v[ic * 8 + 7]) << 16);
        *(uint4*)(orow + ic * 8) = pk;
    }
}

// ---- K4: fused BTT — 2 barriers/kbl, epilogue ∥ phase1(next) overlap ----
__global__ __launch_bounds__(256, 3) void k_fz(const unsigned short* __restrict__ w1m,
                                               const unsigned short* __restrict__ w2m,
                                               const unsigned short* __restrict__ xg3,
                                               const float* __restrict__ bias,
                                               const int* __restrict__ tokmap,
                                               const float* __restrict__ wgt,
                                               const int4* __restrict__ tileDesc,
                                               float* __restrict__ out) {
    __shared__ unsigned short zls[8][2][4][16][8];  // 16 KB: [kk][e][joct][tslot][jj]
    __shared__ float ybuf[16][8][64];               // 32 KB: [t][k][l'] XOR-swizzled

    int bid = blockIdx.x;
    int4 td = tileDesc[bid >> 1];
    int kb0 = (bid & 1) * 4;
    int p = td.x, s0 = td.y, cnt = td.z;
    if (p < 0) return;

    int a0 = 0, r0 = p;
    while (r0 >= 7 - a0) { r0 -= 7 - a0; ++a0; }
    int ea = a0, eb = a0 + 1 + r0;

    int tid = threadIdx.x;
    int w = tid >> 6, l = tid & 63;
    int lr = l & 15, lg = l >> 4;
    int e_lane = lr >> 3, kk = lr & 7;
    int my_e = e_lane ? eb : ea;

    float gs[4];
    #pragma unroll
    for (int r = 0; r < 4; ++r) {
        int tok = tokmap[min(s0 + lg * 4 + r, NTOK - 1)];
        float2 wv = *(const float2*)&wgt[tok * 2];
        gs[r] = e_lane ? wv.y : wv.x;
    }
    int tok4[4];
    #pragma unroll
    for (int tt = 0; tt < 4; ++tt)
        tok4[tt] = tokmap[min(s0 + w * 4 + tt, NTOK - 1)];

    bf16x8 a[8];
    int srow = min(s0 + lr, NTOK - 1);
    #pragma unroll
    for (int jj = 0; jj < 8; ++jj) {
        int j = w * 8 + jj;
        a[jj] = *(const bf16x8*)(xg3 + ((size_t)j * NTOK + srow) * 32 + lg * 8);
    }

    const f32x4 zero4 = {0.f, 0.f, 0.f, 0.f};
    const unsigned short* w1base = w1m + (((size_t)(my_e * 32 + w * 8) * 64) + kk) * 32 + lg * 8;

    bf16x8 w1f[8];
    #pragma unroll
    for (int jj = 0; jj < 8; ++jj)
        w1f[jj] = *(const bf16x8*)(w1base + (size_t)jj * 2048 + (size_t)kb0 * 256);

    // phase1(n): consume w1f (frags for kb0+n) -> zls; prefetch frags n+1
    auto phase1 = [&](int n) {
        f32x4 dj[8];
        #pragma unroll
        for (int jj = 0; jj < 8; ++jj)
            dj[jj] = __builtin_amdgcn_mfma_f32_16x16x32_bf16(a[jj], w1f[jj], zero4, 0, 0, 0);
        if (n + 1 < 4) {
            #pragma unroll
            for (int jj = 0; jj < 8; ++jj)
                w1f[jj] = *(const bf16x8*)(w1base + (size_t)jj * 2048 + (size_t)(kb0 + n + 1) * 256);
        }
        #pragma unroll
        for (int r = 0; r < 4; ++r) {
            float g = gs[r];
            int ts = (lg * 4 + r) ^ kk;
            uint4 pk;
            pk.x = (uint32_t)f2bf(dj[0][r] * g) | ((uint32_t)f2bf(dj[1][r] * g) << 16);
            pk.y = (uint32_t)f2bf(dj[2][r] * g) | ((uint32_t)f2bf(dj[3][r] * g) << 16);
            pk.z = (uint32_t)f2bf(dj[4][r] * g) | ((uint32_t)f2bf(dj[5][r] * g) << 16);
            pk.w = (uint32_t)f2bf(dj[6][r] * g) | ((uint32_t)f2bf(dj[7][r] * g) << 16);
            *(uint4*)&zls[kk][e_lane][w][ts][0] = pk;
        }
    };

    phase1(0);
    __syncthreads();

    for (int kbl = 0; kbl < 4; ++kbl) {
        int kb = kb0 + kbl;

        // ---- phase 2: A = W2 (m=l), B = z (n=token); D -> ybuf ----
        #pragma unroll
        for (int k = 0; k < 8; ++k) {
            int kg = kb * 8 + k;
            bf16x8 az0 = *(const bf16x8*)&zls[k][0][lg][lr ^ k][0];
            bf16x8 az1 = *(const bf16x8*)&zls[k][1][lg][lr ^ k][0];
            bf16x8 b0 = *(const bf16x8*)(w2m + (((size_t)ea * 64 + kg) * 64 + w * 16 + lr) * 32 + lg * 8);
            bf16x8 b1 = *(const bf16x8*)(w2m + (((size_t)eb * 64 + kg) * 64 + w * 16 + lr) * 32 + lg * 8);
            f32x4 acc = __builtin_amdgcn_mfma_f32_16x16x32_bf16(b0, az0, zero4, 0, 0, 0);
            acc = __builtin_amdgcn_mfma_f32_16x16x32_bf16(b1, az1, acc, 0, 0, 0);
            int lp = (w * 16 + lg * 4) ^ ((lr & 3) << 4);
            *(f32x4*)&ybuf[lr][k][lp] = acc;
        }
        __syncthreads();                            // ybuf ready; zls consumed

        if (kbl < 3) phase1(kbl + 1);               // refill zls ∥ epilogue below

        // ---- epilogue: wave-uniform token, contiguous full-line stores ----
        {
            f32x4 bv0 = *(const f32x4*)&bias[kb * 512 + l * 8];
            f32x4 bv1 = *(const f32x4*)&bias[kb * 512 + l * 8 + 4];
            #pragma unroll
            for (int tt = 0; tt < 4; ++tt) {
                int t = w * 4 + tt;
                if (t < cnt) {
                    int kq = l >> 3;
                    int lp = ((l & 7) * 8) ^ ((t & 3) << 4);
                    f32x4 y0 = *(const f32x4*)&ybuf[t][kq][lp];
                    f32x4 y1 = *(const f32x4*)&ybuf[t][kq][lp + 4];
                    f32x4 o0 = y0 + bv0;
                    f32x4 o1 = y1 + bv1;
                    float* dst = out + (size_t)tok4[tt] * OUTD + kb * 512 + l * 8;
                    __builtin_nontemporal_store(o0, (f32x4*)dst);
                    __builtin_nontemporal_store(o1, (f32x4*)(dst + 4));
                }
            }
        }
        if (kbl < 3) __syncthreads();               // zls(new) ready; ybuf free
    }
}

extern "C" void kernel_launch(void* const* d_in, const int* in_sizes, int n_in,
                              void* d_out, int out_size, void* d_ws, size_t ws_size,
                              hipStream_t stream) {
    const float* x  = (const float*)d_in[0];
    const float* Wg = (const float*)d_in[1];
    const float* W1 = (const float*)d_in[2];
    const float* W2 = (const float*)d_in[3];
    const float* b  = (const float*)d_in[4];
    float* out = (float*)d_out;

    unsigned short* w1m = (unsigned short*)d_ws;            // 1 MB
    unsigned short* w2m = w1m + 524288;                     // 2 MB
    unsigned short* xg3 = w2m + 1048576;                    // 16 MB
    int*   tokmap   = (int*)(xg3 + 8388608);                // 8192 i
    float* wgt      = (float*)(tokmap + NTOK);              // 16384 f
    int*   pairCnt  = (int*)(wgt + 2 * NTOK);               // 32 i
    int4*  tileDesc = (int4*)(pairCnt + 32);                // 539 int4
    int*   bucket   = (int*)xg3;                            // aliased: dead before k_xg3 runs

    hipMemsetAsync(pairCnt, 0, 32 * sizeof(int), stream);
    k_prep <<<2208, 256, 0, stream>>>(x, Wg, W1, W2, w1m, w2m, pairCnt, bucket, wgt);
    k_slots<<<32,   256, 0, stream>>>(pairCnt, bucket, tokmap, tileDesc);
    k_xg3  <<<1024, 256, 0, stream>>>(x, tokmap, xg3);
    k_fz   <<<MAXT16 * 2, 256, 0, stream>>>(w1m, w2m, xg3, b, tokmap, wgt, tileDesc, out);
}

// Round 14
// 114.214 us; speedup vs baseline: 1.4404x; 1.4404x over previous
//
#include <hip/hip_runtime.h>
#include <stdint.h>

#define NTOK 8192
#define DIM  1024
#define NE   8
#define NPAIR 28
#define OUTD 4096
#define MAXT16 539   // >= sum_p ceil(cnt_p/16): 512 + 27 worst case

typedef __attribute__((ext_vector_type(8))) short bf16x8;
typedef __attribute__((ext_vector_type(4))) float f32x4;

static __device__ __forceinline__ unsigned short f2bf(float f) {
    uint32_t u = __float_as_uint(f);
    u += 0x7fffu + ((u >> 16) & 1u);     // RNE
    return (unsigned short)(u >> 16);
}

// ---- K1: fused prep. bids 0..31: W1 repack | 32..159: W2 repack | 160..415: gate (32 tok) ----
// w1m[e][j][k][i]  i contiguous : 524288 elems
// w2m[e][k][l][j]  j contiguous : 1048576 elems
__global__ __launch_bounds__(256) void k_prep(const float* __restrict__ x,
                                              const float* __restrict__ Wg,
                                              const float* __restrict__ W1,
                                              const float* __restrict__ W2,
                                              unsigned short* __restrict__ w1m,
                                              unsigned short* __restrict__ w2m,
                                              int* __restrict__ pidTok,
                                              float* __restrict__ wgt) {
    __shared__ float smemf[8448];                   // 33 KB union
    int bid = blockIdx.x;
    int tid = threadIdx.x;

    if (bid < 32) {
        // ================= W1 repack: block j, coalesced both sides =================
        int j = bid;
        unsigned short* lds = (unsigned short*)smemf;   // [32][514] bf16
        const float* src = W1 + (size_t)j * 16384;
        int f0 = tid * 64;
        #pragma unroll
        for (int c = 0; c < 16; ++c) {
            int f = f0 + c * 4;
            float4 v = *(const float4*)&src[f];
            int i = f >> 9, rem = f & 511;
            unsigned short* d = lds + i * 514 + rem;
            d[0] = f2bf(v.x); d[1] = f2bf(v.y); d[2] = f2bf(v.z); d[3] = f2bf(v.w);
        }
        __syncthreads();
        int e = tid >> 5, kp = tid & 31;
        #pragma unroll
        for (int dk = 0; dk < 2; ++dk) {
            int k = kp * 2 + dk;
            uint32_t q[16];
            #pragma unroll
            for (int c = 0; c < 16; ++c) {
                uint32_t lo = lds[(2 * c) * 514 + k * 8 + e];
                uint32_t hi = lds[(2 * c + 1) * 514 + k * 8 + e];
                q[c] = lo | (hi << 16);
            }
            unsigned short* dst = w1m + (((size_t)e * 32 + j) * 64 + k) * 32;
            #pragma unroll
            for (int c = 0; c < 4; ++c) {
                uint4 u; u.x = q[c*4]; u.y = q[c*4+1]; u.z = q[c*4+2]; u.w = q[c*4+3];
                *(uint4*)(dst + c * 8) = u;
            }
        }
    } else if (bid < 160) {
        // ================= W2 repack: block = 4 (e,k) pairs =================
        int ek4 = bid - 32;                         // 0..127
        unsigned short* lds = (unsigned short*)smemf;   // [4][32*66] bf16
        int sub = tid >> 6, l6 = tid & 63;
        const float* s2 = W2 + (size_t)ek4 * 8192 + sub * 2048 + l6 * 32;
        #pragma unroll
        for (int c = 0; c < 32; c += 4) {
            float4 v = *(const float4*)&s2[c];
            int f = l6 * 32 + c;
            int j = f >> 6, l = f & 63;
            unsigned short* d = lds + sub * 2112 + j * 66 + l;
            d[0] = f2bf(v.x); d[1] = f2bf(v.y); d[2] = f2bf(v.z); d[3] = f2bf(v.w);
        }
        __syncthreads();
        uint32_t q[16];
        #pragma unroll
        for (int c = 0; c < 16; ++c) {
            uint32_t lo = lds[sub * 2112 + (2 * c) * 66 + l6];
            uint32_t hi = lds[sub * 2112 + (2 * c + 1) * 66 + l6];
            q[c] = lo | (hi << 16);
        }
        unsigned short* dst = w2m + ((size_t)ek4 * 4 + sub) * 2048 + l6 * 32;
        #pragma unroll
        for (int c = 0; c < 4; ++c) {
            uint4 u; u.x = q[c*4]; u.y = q[c*4+1]; u.z = q[c*4+2]; u.w = q[c*4+3];
            *(uint4*)(dst + c * 8) = u;
        }
    } else {
        // ================= gate: 32 tokens/block, 8 per wave, NO atomics =================
        float* sWg = smemf;                         // [8][1024]
        #pragma unroll
        for (int u = 0; u < 8; ++u) {
            int idx = u * 1024 + tid * 4;
            *(float4*)&sWg[idx] = *(const float4*)&Wg[idx];
        }
        __syncthreads();
        int w = tid >> 6, lane = tid & 63;
        int tokBase = (bid - 160) * 32 + w * 8;
        for (int it = 0; it < 8; ++it) {
            int tok = tokBase + it;
            float acc[NE];
            #pragma unroll
            for (int e = 0; e < NE; ++e) acc[e] = 0.f;
            const float* xr = x + (size_t)tok * DIM;
            #pragma unroll
            for (int c = 0; c < 4; ++c) {
                float4 xv = *(const float4*)&xr[c * 256 + lane * 4];
                #pragma unroll
                for (int e = 0; e < NE; ++e) {
                    float4 wv = *(const float4*)&sWg[e * 1024 + c * 256 + lane * 4];
                    acc[e] += xv.x * wv.x + xv.y * wv.y + xv.z * wv.z + xv.w * wv.w;
                }
            }
            #pragma unroll
            for (int e = 0; e < NE; ++e)
                #pragma unroll
                for (int off = 32; off > 0; off >>= 1)
                    acc[e] += __shfl_xor(acc[e], off, 64);
            if (lane == 0) {
                int i1 = 0; float v1 = acc[0];
                for (int e = 1; e < NE; ++e) if (acc[e] > v1) { v1 = acc[e]; i1 = e; }
                int i2 = -1; float v2 = -3.4e38f;
                for (int e = 0; e < NE; ++e) { if (e == i1) continue; if (acc[e] > v2) { v2 = acc[e]; i2 = e; } }
                float ex = expf(v2 - v1);
                float s  = 1.f / (1.f + ex);
                float w1v = s + 1e-6f;
                float w2v = ex * s + 1e-6f;
                int ea = min(i1, i2), eb = max(i1, i2);
                float wa = (i1 < i2) ? w1v : w2v;
                float wb = (i1 < i2) ? w2v : w1v;
                wgt[tok * 2 + 0] = wa;
                wgt[tok * 2 + 1] = wb;
                pidTok[tok] = ea * 7 - (ea * (ea - 1)) / 2 + (eb - ea - 1);
            }
        }
    }
}

// ---- K2: single-block bucketize (LDS histogram) + tokmap + tileDesc ----
__global__ __launch_bounds__(1024) void k_slots(const int* __restrict__ pidTok,
                                                int* __restrict__ tokmap,
                                                int4* __restrict__ tileDesc) {
    __shared__ int hist[NPAIR], base[NPAIR], cur[NPAIR];
    int tid = threadIdx.x;
    if (tid < NPAIR) { hist[tid] = 0; cur[tid] = 0; }
    __syncthreads();
    for (int i = tid; i < NTOK; i += 1024) atomicAdd(&hist[pidTok[i]], 1);
    __syncthreads();
    if (tid == 0) {
        int off = 0;
        for (int p = 0; p < NPAIR; ++p) { base[p] = off; off += hist[p]; }
    }
    __syncthreads();
    for (int i = tid; i < NTOK; i += 1024) {
        int p = pidTok[i];
        int pos = atomicAdd(&cur[p], 1);
        tokmap[base[p] + pos] = i;
    }
    __syncthreads();
    for (int s = tid; s < MAXT16; s += 1024) {
        int4 d; d.x = -1; d.y = 0; d.z = 0; d.w = 0;
        int toff = 0, soff = 0;
        for (int q = 0; q < NPAIR; ++q) {
            int c = hist[q];
            int nt = (c + 15) >> 4;
            if (d.x < 0 && s < toff + nt) {
                int lt = s - toff;
                d.x = q;
                d.y = soff + lt * 16;
                d.z = min(16, c - lt * 16);
            }
            toff += nt; soff += c;
        }
        tileDesc[s] = d;
    }
}

// ---- K3: gather x -> xg3[j][slot][i] bf16 (64-B rows), LDS transpose ----
__global__ __launch_bounds__(256) void k_xg3(const float* __restrict__ x,
                                             const int* __restrict__ tokmap,
                                             unsigned short* __restrict__ xg3) {
    __shared__ float tile[8][1056];                 // pad +1 per 32
    int s0 = blockIdx.x * 8;
    int tid = threadIdx.x;
    int r = tid >> 5, c = tid & 31;
    int tok = tokmap[s0 + r];
    const float* xr = x + (size_t)tok * DIM;
    #pragma unroll
    for (int u = 0; u < 8; ++u) {
        int d = u * 128 + c * 4;
        float4 v = *(const float4*)&xr[d];
        int d2 = d + (d >> 5);
        tile[r][d2 + 0] = v.x; tile[r][d2 + 1] = v.y;
        tile[r][d2 + 2] = v.z; tile[r][d2 + 3] = v.w;
    }
    __syncthreads();
    int sl = tid >> 5, j = tid & 31;
    float v[32];
    #pragma unroll
    for (int i = 0; i < 32; ++i) v[i] = tile[sl][i * 33 + j];
    unsigned short* orow = xg3 + ((size_t)j * NTOK + s0 + sl) * 32;
    #pragma unroll
    for (int ic = 0; ic < 4; ++ic) {
        uint4 pk;
        pk.x = (uint32_t)f2bf(v[ic * 8 + 0]) | ((uint32_t)f2bf(v[ic * 8 + 1]) << 16);
        pk.y = (uint32_t)f2bf(v[ic * 8 + 2]) | ((uint32_t)f2bf(v[ic * 8 + 3]) << 16);
        pk.z = (uint32_t)f2bf(v[ic * 8 + 4]) | ((uint32_t)f2bf(v[ic * 8 + 5]) << 16);
        pk.w = (uint32_t)f2bf(v[ic * 8 + 6]) | ((uint32_t)f2bf(v[ic * 8 + 7]) << 16);
        *(uint4*)(orow + ic * 8) = pk;
    }
}

// ---- K4: fused BTT — 2 barriers/kbl, epilogue ∥ phase1(next) overlap ----
__global__ __launch_bounds__(256, 3) void k_fz(const unsigned short* __restrict__ w1m,
                                               const unsigned short* __restrict__ w2m,
                                               const unsigned short* __restrict__ xg3,
                                               const float* __restrict__ bias,
                                               const int* __restrict__ tokmap,
                                               const float* __restrict__ wgt,
                                               const int4* __restrict__ tileDesc,
                                               float* __restrict__ out) {
    __shared__ unsigned short zls[8][2][4][16][8];  // 16 KB: [kk][e][joct][tslot][jj]
    __shared__ float ybuf[16][8][64];               // 32 KB: [t][k][l'] XOR-swizzled

    int bid = blockIdx.x;
    int4 td = tileDesc[bid >> 1];
    int kb0 = (bid & 1) * 4;
    int p = td.x, s0 = td.y, cnt = td.z;
    if (p < 0) return;

    int a0 = 0, r0 = p;
    while (r0 >= 7 - a0) { r0 -= 7 - a0; ++a0; }
    int ea = a0, eb = a0 + 1 + r0;

    int tid = threadIdx.x;
    int w = tid >> 6, l = tid & 63;
    int lr = l & 15, lg = l >> 4;
    int e_lane = lr >> 3, kk = lr & 7;
    int my_e = e_lane ? eb : ea;

    float gs[4];
    #pragma unroll
    for (int r = 0; r < 4; ++r) {
        int tok = tokmap[min(s0 + lg * 4 + r, NTOK - 1)];
        float2 wv = *(const float2*)&wgt[tok * 2];
        gs[r] = e_lane ? wv.y : wv.x;
    }
    int tok4[4];
    #pragma unroll
    for (int tt = 0; tt < 4; ++tt)
        tok4[tt] = tokmap[min(s0 + w * 4 + tt, NTOK - 1)];

    bf16x8 a[8];
    int srow = min(s0 + lr, NTOK - 1);
    #pragma unroll
    for (int jj = 0; jj < 8; ++jj) {
        int j = w * 8 + jj;
        a[jj] = *(const bf16x8*)(xg3 + ((size_t)j * NTOK + srow) * 32 + lg * 8);
    }

    const f32x4 zero4 = {0.f, 0.f, 0.f, 0.f};
    const unsigned short* w1base = w1m + (((size_t)(my_e * 32 + w * 8) * 64) + kk) * 32 + lg * 8;

    bf16x8 w1f[8];
    #pragma unroll
    for (int jj = 0; jj < 8; ++jj)
        w1f[jj] = *(const bf16x8*)(w1base + (size_t)jj * 2048 + (size_t)kb0 * 256);

    auto phase1 = [&](int n) {
        f32x4 dj[8];
        #pragma unroll
        for (int jj = 0; jj < 8; ++jj)
            dj[jj] = __builtin_amdgcn_mfma_f32_16x16x32_bf16(a[jj], w1f[jj], zero4, 0, 0, 0);
        if (n + 1 < 4) {
            #pragma unroll
            for (int jj = 0; jj < 8; ++jj)
                w1f[jj] = *(const bf16x8*)(w1base + (size_t)jj * 2048 + (size_t)(kb0 + n + 1) * 256);
        }
        #pragma unroll
        for (int r = 0; r < 4; ++r) {
            float g = gs[r];
            int ts = (lg * 4 + r) ^ kk;
            uint4 pk;
            pk.x = (uint32_t)f2bf(dj[0][r] * g) | ((uint32_t)f2bf(dj[1][r] * g) << 16);
            pk.y = (uint32_t)f2bf(dj[2][r] * g) | ((uint32_t)f2bf(dj[3][r] * g) << 16);
            pk.z = (uint32_t)f2bf(dj[4][r] * g) | ((uint32_t)f2bf(dj[5][r] * g) << 16);
            pk.w = (uint32_t)f2bf(dj[6][r] * g) | ((uint32_t)f2bf(dj[7][r] * g) << 16);
            *(uint4*)&zls[kk][e_lane][w][ts][0] = pk;
        }
    };

    phase1(0);
    __syncthreads();

    for (int kbl = 0; kbl < 4; ++kbl) {
        int kb = kb0 + kbl;

        #pragma unroll
        for (int k = 0; k < 8; ++k) {
            int kg = kb * 8 + k;
            bf16x8 az0 = *(const bf16x8*)&zls[k][0][lg][lr ^ k][0];
            bf16x8 az1 = *(const bf16x8*)&zls[k][1][lg][lr ^ k][0];
            bf16x8 b0 = *(const bf16x8*)(w2m + (((size_t)ea * 64 + kg) * 64 + w * 16 + lr) * 32 + lg * 8);
            bf16x8 b1 = *(const bf16x8*)(w2m + (((size_t)eb * 64 + kg) * 64 + w * 16 + lr) * 32 + lg * 8);
            f32x4 acc = __builtin_amdgcn_mfma_f32_16x16x32_bf16(b0, az0, zero4, 0, 0, 0);
            acc = __builtin_amdgcn_mfma_f32_16x16x32_bf16(b1, az1, acc, 0, 0, 0);
            int lp = (w * 16 + lg * 4) ^ ((lr & 3) << 4);
            *(f32x4*)&ybuf[lr][k][lp] = acc;
        }
        __syncthreads();                            // ybuf ready; zls consumed

        if (kbl < 3) phase1(kbl + 1);               // refill zls ∥ epilogue below

        {
            f32x4 bv0 = *(const f32x4*)&bias[kb * 512 + l * 8];
            f32x4 bv1 = *(const f32x4*)&bias[kb * 512 + l * 8 + 4];
            #pragma unroll
            for (int tt = 0; tt < 4; ++tt) {
                int t = w * 4 + tt;
                if (t < cnt) {
                    int kq = l >> 3;
                    int lp = ((l & 7) * 8) ^ ((t & 3) << 4);
                    f32x4 y0 = *(const f32x4*)&ybuf[t][kq][lp];
                    f32x4 y1 = *(const f32x4*)&ybuf[t][kq][lp + 4];
                    f32x4 o0 = y0 + bv0;
                    f32x4 o1 = y1 + bv1;
                    float* dst = out + (size_t)tok4[tt] * OUTD + kb * 512 + l * 8;
                    __builtin_nontemporal_store(o0, (f32x4*)dst);
                    __builtin_nontemporal_store(o1, (f32x4*)(dst + 4));
                }
            }
        }
        if (kbl < 3) __syncthreads();               // zls(new) ready; ybuf free
    }
}

extern "C" void kernel_launch(void* const* d_in, const int* in_sizes, int n_in,
                              void* d_out, int out_size, void* d_ws, size_t ws_size,
                              hipStream_t stream) {
    const float* x  = (const float*)d_in[0];
    const float* Wg = (const float*)d_in[1];
    const float* W1 = (const float*)d_in[2];
    const float* W2 = (const float*)d_in[3];
    const float* b  = (const float*)d_in[4];
    float* out = (float*)d_out;

    unsigned short* w1m = (unsigned short*)d_ws;            // 1 MB
    unsigned short* w2m = w1m + 524288;                     // 2 MB
    unsigned short* xg3 = w2m + 1048576;                    // 16 MB
    int*   tokmap   = (int*)(xg3 + 8388608);                // 8192 i
    float* wgt      = (float*)(tokmap + NTOK);              // 16384 f
    int4*  tileDesc = (int4*)(wgt + 2 * NTOK);              // 539 int4
    int*   pidTok   = (int*)(tileDesc + MAXT16);            // 8192 i

    k_prep <<<416,  256, 0, stream>>>(x, Wg, W1, W2, w1m, w2m, pidTok, wgt);
    k_slots<<<1,   1024, 0, stream>>>(pidTok, tokmap, tileDesc);
    k_xg3  <<<1024, 256, 0, stream>>>(x, tokmap, xg3);
    k_fz   <<<MAXT16 * 2, 256, 0, stream>>>(w1m, w2m, xg3, b, tokmap, wgt, tileDesc, out);
}

// Round 15
// 112.373 us; speedup vs baseline: 1.4640x; 1.0164x over previous
//
#include <hip/hip_runtime.h>
#include <stdint.h>

#define NTOK 8192
#define DIM  1024
#define NE   8
#define NPAIR 28
#define OUTD 4096
#define MAXT16 539   // >= sum_p ceil(cnt_p/16): 512 + 27 worst case

typedef __attribute__((ext_vector_type(8))) short bf16x8;
typedef __attribute__((ext_vector_type(4))) float f32x4;

static __device__ __forceinline__ unsigned short f2bf(float f) {
    uint32_t u = __float_as_uint(f);
    u += 0x7fffu + ((u >> 16) & 1u);     // RNE
    return (unsigned short)(u >> 16);
}

// ---- K1: fused prep. bids 0..31: W1 repack | 32..159: W2 repack | 160..415: gate (32 tok) ----
// w1m[e][j][k][i]  i contiguous : 524288 elems
// w2m[e][k][l][j]  j contiguous : 1048576 elems
__global__ __launch_bounds__(256) void k_prep(const float* __restrict__ x,
                                              const float* __restrict__ Wg,
                                              const float* __restrict__ W1,
                                              const float* __restrict__ W2,
                                              unsigned short* __restrict__ w1m,
                                              unsigned short* __restrict__ w2m,
                                              int* __restrict__ pidTok,
                                              float* __restrict__ wgt) {
    __shared__ float smemf[8448];                   // 33 KB union
    int bid = blockIdx.x;
    int tid = threadIdx.x;

    if (bid < 32) {
        // ================= W1 repack: block j, coalesced both sides =================
        int j = bid;
        unsigned short* lds = (unsigned short*)smemf;   // [32][514] bf16
        const float* src = W1 + (size_t)j * 16384;
        int f0 = tid * 64;
        #pragma unroll
        for (int c = 0; c < 16; ++c) {
            int f = f0 + c * 4;
            float4 v = *(const float4*)&src[f];
            int i = f >> 9, rem = f & 511;
            unsigned short* d = lds + i * 514 + rem;
            d[0] = f2bf(v.x); d[1] = f2bf(v.y); d[2] = f2bf(v.z); d[3] = f2bf(v.w);
        }
        __syncthreads();
        int e = tid >> 5, kp = tid & 31;
        #pragma unroll
        for (int dk = 0; dk < 2; ++dk) {
            int k = kp * 2 + dk;
            uint32_t q[16];
            #pragma unroll
            for (int c = 0; c < 16; ++c) {
                uint32_t lo = lds[(2 * c) * 514 + k * 8 + e];
                uint32_t hi = lds[(2 * c + 1) * 514 + k * 8 + e];
                q[c] = lo | (hi << 16);
            }
            unsigned short* dst = w1m + (((size_t)e * 32 + j) * 64 + k) * 32;
            #pragma unroll
            for (int c = 0; c < 4; ++c) {
                uint4 u; u.x = q[c*4]; u.y = q[c*4+1]; u.z = q[c*4+2]; u.w = q[c*4+3];
                *(uint4*)(dst + c * 8) = u;
            }
        }
    } else if (bid < 160) {
        // ================= W2 repack: block = 4 (e,k) pairs =================
        int ek4 = bid - 32;                         // 0..127
        unsigned short* lds = (unsigned short*)smemf;   // [4][32*66] bf16
        int sub = tid >> 6, l6 = tid & 63;
        const float* s2 = W2 + (size_t)ek4 * 8192 + sub * 2048 + l6 * 32;
        #pragma unroll
        for (int c = 0; c < 32; c += 4) {
            float4 v = *(const float4*)&s2[c];
            int f = l6 * 32 + c;
            int j = f >> 6, l = f & 63;
            unsigned short* d = lds + sub * 2112 + j * 66 + l;
            d[0] = f2bf(v.x); d[1] = f2bf(v.y); d[2] = f2bf(v.z); d[3] = f2bf(v.w);
        }
        __syncthreads();
        uint32_t q[16];
        #pragma unroll
        for (int c = 0; c < 16; ++c) {
            uint32_t lo = lds[sub * 2112 + (2 * c) * 66 + l6];
            uint32_t hi = lds[sub * 2112 + (2 * c + 1) * 66 + l6];
            q[c] = lo | (hi << 16);
        }
        unsigned short* dst = w2m + ((size_t)ek4 * 4 + sub) * 2048 + l6 * 32;
        #pragma unroll
        for (int c = 0; c < 4; ++c) {
            uint4 u; u.x = q[c*4]; u.y = q[c*4+1]; u.z = q[c*4+2]; u.w = q[c*4+3];
            *(uint4*)(dst + c * 8) = u;
        }
    } else {
        // ================= gate: 32 tokens/block, 8 per wave, NO atomics =================
        float* sWg = smemf;                         // [8][1024]
        #pragma unroll
        for (int u = 0; u < 8; ++u) {
            int idx = u * 1024 + tid * 4;
            *(float4*)&sWg[idx] = *(const float4*)&Wg[idx];
        }
        __syncthreads();
        int w = tid >> 6, lane = tid & 63;
        int tokBase = (bid - 160) * 32 + w * 8;
        for (int it = 0; it < 8; ++it) {
            int tok = tokBase + it;
            float acc[NE];
            #pragma unroll
            for (int e = 0; e < NE; ++e) acc[e] = 0.f;
            const float* xr = x + (size_t)tok * DIM;
            #pragma unroll
            for (int c = 0; c < 4; ++c) {
                float4 xv = *(const float4*)&xr[c * 256 + lane * 4];
                #pragma unroll
                for (int e = 0; e < NE; ++e) {
                    float4 wv = *(const float4*)&sWg[e * 1024 + c * 256 + lane * 4];
                    acc[e] += xv.x * wv.x + xv.y * wv.y + xv.z * wv.z + xv.w * wv.w;
                }
            }
            #pragma unroll
            for (int e = 0; e < NE; ++e)
                #pragma unroll
                for (int off = 32; off > 0; off >>= 1)
                    acc[e] += __shfl_xor(acc[e], off, 64);
            if (lane == 0) {
                int i1 = 0; float v1 = acc[0];
                for (int e = 1; e < NE; ++e) if (acc[e] > v1) { v1 = acc[e]; i1 = e; }
                int i2 = -1; float v2 = -3.4e38f;
                for (int e = 0; e < NE; ++e) { if (e == i1) continue; if (acc[e] > v2) { v2 = acc[e]; i2 = e; } }
                float ex = expf(v2 - v1);
                float s  = 1.f / (1.f + ex);
                float w1v = s + 1e-6f;
                float w2v = ex * s + 1e-6f;
                int ea = min(i1, i2), eb = max(i1, i2);
                float wa = (i1 < i2) ? w1v : w2v;
                float wb = (i1 < i2) ? w2v : w1v;
                wgt[tok * 2 + 0] = wa;
                wgt[tok * 2 + 1] = wb;
                pidTok[tok] = ea * 7 - (ea * (ea - 1)) / 2 + (eb - ea - 1);
            }
        }
    }
}

// ---- K2: single-block bucketize (LDS histogram) + tokmap + tileDesc ----
__global__ __launch_bounds__(1024) void k_slots(const int* __restrict__ pidTok,
                                                int* __restrict__ tokmap,
                                                int4* __restrict__ tileDesc) {
    __shared__ int hist[NPAIR], base[NPAIR], cur[NPAIR];
    int tid = threadIdx.x;
    if (tid < NPAIR) { hist[tid] = 0; cur[tid] = 0; }
    __syncthreads();
    for (int i = tid; i < NTOK; i += 1024) atomicAdd(&hist[pidTok[i]], 1);
    __syncthreads();
    if (tid == 0) {
        int off = 0;
        for (int p = 0; p < NPAIR; ++p) { base[p] = off; off += hist[p]; }
    }
    __syncthreads();
    for (int i = tid; i < NTOK; i += 1024) {
        int p = pidTok[i];
        int pos = atomicAdd(&cur[p], 1);
        tokmap[base[p] + pos] = i;
    }
    __syncthreads();
    for (int s = tid; s < MAXT16; s += 1024) {
        int4 d; d.x = -1; d.y = 0; d.z = 0; d.w = 0;
        int toff = 0, soff = 0;
        for (int q = 0; q < NPAIR; ++q) {
            int c = hist[q];
            int nt = (c + 15) >> 4;
            if (d.x < 0 && s < toff + nt) {
                int lt = s - toff;
                d.x = q;
                d.y = soff + lt * 16;
                d.z = min(16, c - lt * 16);
            }
            toff += nt; soff += c;
        }
        tileDesc[s] = d;
    }
}

// ---- K3: gather x -> xg3[j][slot][i] bf16 (64-B rows), LDS transpose ----
__global__ __launch_bounds__(256) void k_xg3(const float* __restrict__ x,
                                             const int* __restrict__ tokmap,
                                             unsigned short* __restrict__ xg3) {
    __shared__ float tile[8][1056];                 // pad +1 per 32
    int s0 = blockIdx.x * 8;
    int tid = threadIdx.x;
    int r = tid >> 5, c = tid & 31;
    int tok = tokmap[s0 + r];
    const float* xr = x + (size_t)tok * DIM;
    #pragma unroll
    for (int u = 0; u < 8; ++u) {
        int d = u * 128 + c * 4;
        float4 v = *(const float4*)&xr[d];
        int d2 = d + (d >> 5);
        tile[r][d2 + 0] = v.x; tile[r][d2 + 1] = v.y;
        tile[r][d2 + 2] = v.z; tile[r][d2 + 3] = v.w;
    }
    __syncthreads();
    int sl = tid >> 5, j = tid & 31;
    float v[32];
    #pragma unroll
    for (int i = 0; i < 32; ++i) v[i] = tile[sl][i * 33 + j];
    unsigned short* orow = xg3 + ((size_t)j * NTOK + s0 + sl) * 32;
    #pragma unroll
    for (int ic = 0; ic < 4; ++ic) {
        uint4 pk;
        pk.x = (uint32_t)f2bf(v[ic * 8 + 0]) | ((uint32_t)f2bf(v[ic * 8 + 1]) << 16);
        pk.y = (uint32_t)f2bf(v[ic * 8 + 2]) | ((uint32_t)f2bf(v[ic * 8 + 3]) << 16);
        pk.z = (uint32_t)f2bf(v[ic * 8 + 4]) | ((uint32_t)f2bf(v[ic * 8 + 5]) << 16);
        pk.w = (uint32_t)f2bf(v[ic * 8 + 6]) | ((uint32_t)f2bf(v[ic * 8 + 7]) << 16);
        *(uint4*)(orow + ic * 8) = pk;
    }
}

// ---- K4: fused BTT — k-quarter split (2 kb/block), bank-balanced ybuf swizzle ----
// bid>>2 = 16-token tile, bid&3 = k-quarter. XCD = bid%8: each XCD sees a
// 512 KB L2-resident W2 k-slice.
__global__ __launch_bounds__(256, 3) void k_fz(const unsigned short* __restrict__ w1m,
                                               const unsigned short* __restrict__ w2m,
                                               const unsigned short* __restrict__ xg3,
                                               const float* __restrict__ bias,
                                               const int* __restrict__ tokmap,
                                               const float* __restrict__ wgt,
                                               const int4* __restrict__ tileDesc,
                                               float* __restrict__ out) {
    __shared__ unsigned short zls[8][2][4][16][8];  // 16 KB: [kk][e][joct][tslot][jj]
    __shared__ float ybuf[8192];                    // 32 KB: [t][128 quads][4], quad-swizzled

    int bid = blockIdx.x;
    int4 td = tileDesc[bid >> 2];
    int kb0 = (bid & 3) * 2;
    int p = td.x, s0 = td.y, cnt = td.z;
    if (p < 0) return;

    int a0 = 0, r0 = p;
    while (r0 >= 7 - a0) { r0 -= 7 - a0; ++a0; }
    int ea = a0, eb = a0 + 1 + r0;

    int tid = threadIdx.x;
    int w = tid >> 6, l = tid & 63;
    int lr = l & 15, lg = l >> 4;
    int e_lane = lr >> 3, kk = lr & 7;
    int my_e = e_lane ? eb : ea;

    float gs[4];
    #pragma unroll
    for (int r = 0; r < 4; ++r) {
        int tok = tokmap[min(s0 + lg * 4 + r, NTOK - 1)];
        float2 wv = *(const float2*)&wgt[tok * 2];
        gs[r] = e_lane ? wv.y : wv.x;
    }
    int tok4[4];
    #pragma unroll
    for (int tt = 0; tt < 4; ++tt)
        tok4[tt] = tokmap[min(s0 + w * 4 + tt, NTOK - 1)];

    bf16x8 a[8];
    int srow = min(s0 + lr, NTOK - 1);
    #pragma unroll
    for (int jj = 0; jj < 8; ++jj) {
        int j = w * 8 + jj;
        a[jj] = *(const bf16x8*)(xg3 + ((size_t)j * NTOK + srow) * 32 + lg * 8);
    }

    const f32x4 zero4 = {0.f, 0.f, 0.f, 0.f};
    const unsigned short* w1base = w1m + (((size_t)(my_e * 32 + w * 8) * 64) + kk) * 32 + lg * 8;

    bf16x8 w1f[8];
    #pragma unroll
    for (int jj = 0; jj < 8; ++jj)
        w1f[jj] = *(const bf16x8*)(w1base + (size_t)jj * 2048 + (size_t)kb0 * 256);

    auto phase1 = [&](int n) {
        f32x4 dj[8];
        #pragma unroll
        for (int jj = 0; jj < 8; ++jj)
            dj[jj] = __builtin_amdgcn_mfma_f32_16x16x32_bf16(a[jj], w1f[jj], zero4, 0, 0, 0);
        if (n + 1 < 2) {
            #pragma unroll
            for (int jj = 0; jj < 8; ++jj)
                w1f[jj] = *(const bf16x8*)(w1base + (size_t)jj * 2048 + (size_t)(kb0 + n + 1) * 256);
        }
        #pragma unroll
        for (int r = 0; r < 4; ++r) {
            float g = gs[r];
            int ts = (lg * 4 + r) ^ kk;
            uint4 pk;
            pk.x = (uint32_t)f2bf(dj[0][r] * g) | ((uint32_t)f2bf(dj[1][r] * g) << 16);
            pk.y = (uint32_t)f2bf(dj[2][r] * g) | ((uint32_t)f2bf(dj[3][r] * g) << 16);
            pk.z = (uint32_t)f2bf(dj[4][r] * g) | ((uint32_t)f2bf(dj[5][r] * g) << 16);
            pk.w = (uint32_t)f2bf(dj[6][r] * g) | ((uint32_t)f2bf(dj[7][r] * g) << 16);
            *(uint4*)&zls[kk][e_lane][w][ts][0] = pk;
        }
    };

    phase1(0);
    __syncthreads();

    for (int kbl = 0; kbl < 2; ++kbl) {
        int kb = kb0 + kbl;

        // ---- phase 2: A = W2 (m=l), B = z (n=token); D -> ybuf quads ----
        #pragma unroll
        for (int k = 0; k < 8; ++k) {
            int kg = kb * 8 + k;
            bf16x8 az0 = *(const bf16x8*)&zls[k][0][lg][lr ^ k][0];
            bf16x8 az1 = *(const bf16x8*)&zls[k][1][lg][lr ^ k][0];
            bf16x8 b0 = *(const bf16x8*)(w2m + (((size_t)ea * 64 + kg) * 64 + w * 16 + lr) * 32 + lg * 8);
            bf16x8 b1 = *(const bf16x8*)(w2m + (((size_t)eb * 64 + kg) * 64 + w * 16 + lr) * 32 + lg * 8);
            f32x4 acc = __builtin_amdgcn_mfma_f32_16x16x32_bf16(b0, az0, zero4, 0, 0, 0);
            acc = __builtin_amdgcn_mfma_f32_16x16x32_bf16(b1, az1, acc, 0, 0, 0);
            // lane: token=lr, l' = w*16+lg*4; logical quad = k*16 + w*4 + lg
            int pq = (k * 16 + w * 4 + lg) ^ (k & 1) ^ (lr & 7);
            *(f32x4*)&ybuf[lr * 512 + pq * 4] = acc;
        }
        __syncthreads();                            // ybuf ready; zls consumed

        if (kbl < 1) phase1(kbl + 1);               // refill zls ∥ epilogue below

        // ---- epilogue: wave-uniform token, full-line contiguous stores ----
        {
            f32x4 bv0 = *(const f32x4*)&bias[kb * 512 + l * 8];
            f32x4 bv1 = *(const f32x4*)&bias[kb * 512 + l * 8 + 4];
            int kq = l >> 3;
            int rbase = kq * 16 + (l & 7) * 2;
            #pragma unroll
            for (int tt = 0; tt < 4; ++tt) {
                int t = w * 4 + tt;
                if (t < cnt) {
                    int c = (kq & 1) ^ (t & 7);
                    f32x4 y0 = *(const f32x4*)&ybuf[t * 512 + ((rbase) ^ c) * 4];
                    f32x4 y1 = *(const f32x4*)&ybuf[t * 512 + ((rbase + 1) ^ c) * 4];
                    f32x4 o0 = y0 + bv0;
                    f32x4 o1 = y1 + bv1;
                    float* dst = out + (size_t)tok4[tt] * OUTD + kb * 512 + l * 8;
                    __builtin_nontemporal_store(o0, (f32x4*)dst);
                    __builtin_nontemporal_store(o1, (f32x4*)(dst + 4));
                }
            }
        }
        if (kbl < 1) __syncthreads();               // zls(new) ready; ybuf free
    }
}

extern "C" void kernel_launch(void* const* d_in, const int* in_sizes, int n_in,
                              void* d_out, int out_size, void* d_ws, size_t ws_size,
                              hipStream_t stream) {
    const float* x  = (const float*)d_in[0];
    const float* Wg = (const float*)d_in[1];
    const float* W1 = (const float*)d_in[2];
    const float* W2 = (const float*)d_in[3];
    const float* b  = (const float*)d_in[4];
    float* out = (float*)d_out;

    unsigned short* w1m = (unsigned short*)d_ws;            // 1 MB
    unsigned short* w2m = w1m + 524288;                     // 2 MB
    unsigned short* xg3 = w2m + 1048576;                    // 16 MB
    int*   tokmap   = (int*)(xg3 + 8388608);                // 8192 i
    float* wgt      = (float*)(tokmap + NTOK);              // 16384 f
    int4*  tileDesc = (int4*)(wgt + 2 * NTOK);              // 539 int4
    int*   pidTok   = (int*)(tileDesc + MAXT16);            // 8192 i

    k_prep <<<416,  256, 0, stream>>>(x, Wg, W1, W2, w1m, w2m, pidTok, wgt);
    k_slots<<<1,   1024, 0, stream>>>(pidTok, tokmap, tileDesc);
    k_xg3  <<<1024, 256, 0, stream>>>(x, tokmap, xg3);
    k_fz   <<<MAXT16 * 4, 256, 0, stream>>>(w1m, w2m, xg3, b, tokmap, wgt, tileDesc, out);
}

// Round 16
// 98.287 us; speedup vs baseline: 1.6738x; 1.1433x over previous
//
#include <hip/hip_runtime.h>
#include <stdint.h>

#define NTOK 8192
#define DIM  1024
#define NE   8
#define NPAIR 28
#define OUTD 4096
#define MAXT16 539   // >= sum_p ceil(cnt_p/16): 512 + 27 worst case

typedef __attribute__((ext_vector_type(8))) short bf16x8;
typedef __attribute__((ext_vector_type(4))) float f32x4;

static __device__ __forceinline__ unsigned short f2bf(float f) {
    uint32_t u = __float_as_uint(f);
    u += 0x7fffu + ((u >> 16) & 1u);     // RNE
    return (unsigned short)(u >> 16);
}

// LDS-only barrier: wait DS ops, NOT vmcnt (stores/loads in flight stay in flight).
static __device__ __forceinline__ void barrier_lds() {
    asm volatile("s_waitcnt lgkmcnt(0)\n\ts_barrier" ::: "memory");
}

// ---- K1: fused prep. bids 0..31: W1 repack | 32..159: W2 repack | 160..415: gate (32 tok) ----
// w1m[e][j][k][i]  i contiguous : 524288 elems
// w2m[e][k][l][j]  j contiguous : 1048576 elems
__global__ __launch_bounds__(256) void k_prep(const float* __restrict__ x,
                                              const float* __restrict__ Wg,
                                              const float* __restrict__ W1,
                                              const float* __restrict__ W2,
                                              unsigned short* __restrict__ w1m,
                                              unsigned short* __restrict__ w2m,
                                              int* __restrict__ pidTok,
                                              float* __restrict__ wgt) {
    __shared__ float smemf[8448];                   // 33 KB union
    int bid = blockIdx.x;
    int tid = threadIdx.x;

    if (bid < 32) {
        // ================= W1 repack: block j, coalesced both sides =================
        int j = bid;
        unsigned short* lds = (unsigned short*)smemf;   // [32][514] bf16
        const float* src = W1 + (size_t)j * 16384;
        int f0 = tid * 64;
        #pragma unroll
        for (int c = 0; c < 16; ++c) {
            int f = f0 + c * 4;
            float4 v = *(const float4*)&src[f];
            int i = f >> 9, rem = f & 511;
            unsigned short* d = lds + i * 514 + rem;
            d[0] = f2bf(v.x); d[1] = f2bf(v.y); d[2] = f2bf(v.z); d[3] = f2bf(v.w);
        }
        __syncthreads();
        int e = tid >> 5, kp = tid & 31;
        #pragma unroll
        for (int dk = 0; dk < 2; ++dk) {
            int k = kp * 2 + dk;
            uint32_t q[16];
            #pragma unroll
            for (int c = 0; c < 16; ++c) {
                uint32_t lo = lds[(2 * c) * 514 + k * 8 + e];
                uint32_t hi = lds[(2 * c + 1) * 514 + k * 8 + e];
                q[c] = lo | (hi << 16);
            }
            unsigned short* dst = w1m + (((size_t)e * 32 + j) * 64 + k) * 32;
            #pragma unroll
            for (int c = 0; c < 4; ++c) {
                uint4 u; u.x = q[c*4]; u.y = q[c*4+1]; u.z = q[c*4+2]; u.w = q[c*4+3];
                *(uint4*)(dst + c * 8) = u;
            }
        }
    } else if (bid < 160) {
        // ================= W2 repack: block = 4 (e,k) pairs =================
        int ek4 = bid - 32;                         // 0..127
        unsigned short* lds = (unsigned short*)smemf;   // [4][32*66] bf16
        int sub = tid >> 6, l6 = tid & 63;
        const float* s2 = W2 + (size_t)ek4 * 8192 + sub * 2048 + l6 * 32;
        #pragma unroll
        for (int c = 0; c < 32; c += 4) {
            float4 v = *(const float4*)&s2[c];
            int f = l6 * 32 + c;
            int j = f >> 6, l = f & 63;
            unsigned short* d = lds + sub * 2112 + j * 66 + l;
            d[0] = f2bf(v.x); d[1] = f2bf(v.y); d[2] = f2bf(v.z); d[3] = f2bf(v.w);
        }
        __syncthreads();
        uint32_t q[16];
        #pragma unroll
        for (int c = 0; c < 16; ++c) {
            uint32_t lo = lds[sub * 2112 + (2 * c) * 66 + l6];
            uint32_t hi = lds[sub * 2112 + (2 * c + 1) * 66 + l6];
            q[c] = lo | (hi << 16);
        }
        unsigned short* dst = w2m + ((size_t)ek4 * 4 + sub) * 2048 + l6 * 32;
        #pragma unroll
        for (int c = 0; c < 4; ++c) {
            uint4 u; u.x = q[c*4]; u.y = q[c*4+1]; u.z = q[c*4+2]; u.w = q[c*4+3];
            *(uint4*)(dst + c * 8) = u;
        }
    } else {
        // ================= gate: 32 tokens/block, 8 per wave, NO atomics =================
        float* sWg = smemf;                         // [8][1024]
        #pragma unroll
        for (int u = 0; u < 8; ++u) {
            int idx = u * 1024 + tid * 4;
            *(float4*)&sWg[idx] = *(const float4*)&Wg[idx];
        }
        __syncthreads();
        int w = tid >> 6, lane = tid & 63;
        int tokBase = (bid - 160) * 32 + w * 8;
        for (int it = 0; it < 8; ++it) {
            int tok = tokBase + it;
            float acc[NE];
            #pragma unroll
            for (int e = 0; e < NE; ++e) acc[e] = 0.f;
            const float* xr = x + (size_t)tok * DIM;
            #pragma unroll
            for (int c = 0; c < 4; ++c) {
                float4 xv = *(const float4*)&xr[c * 256 + lane * 4];
                #pragma unroll
                for (int e = 0; e < NE; ++e) {
                    float4 wv = *(const float4*)&sWg[e * 1024 + c * 256 + lane * 4];
                    acc[e] += xv.x * wv.x + xv.y * wv.y + xv.z * wv.z + xv.w * wv.w;
                }
            }
            #pragma unroll
            for (int e = 0; e < NE; ++e)
                #pragma unroll
                for (int off = 32; off > 0; off >>= 1)
                    acc[e] += __shfl_xor(acc[e], off, 64);
            if (lane == 0) {
                int i1 = 0; float v1 = acc[0];
                for (int e = 1; e < NE; ++e) if (acc[e] > v1) { v1 = acc[e]; i1 = e; }
                int i2 = -1; float v2 = -3.4e38f;
                for (int e = 0; e < NE; ++e) { if (e == i1) continue; if (acc[e] > v2) { v2 = acc[e]; i2 = e; } }
                float ex = expf(v2 - v1);
                float s  = 1.f / (1.f + ex);
                float w1v = s + 1e-6f;
                float w2v = ex * s + 1e-6f;
                int ea = min(i1, i2), eb = max(i1, i2);
                float wa = (i1 < i2) ? w1v : w2v;
                float wb = (i1 < i2) ? w2v : w1v;
                wgt[tok * 2 + 0] = wa;
                wgt[tok * 2 + 1] = wb;
                pidTok[tok] = ea * 7 - (ea * (ea - 1)) / 2 + (eb - ea - 1);
            }
        }
    }
}

// ---- K2: single-block bucketize (LDS histogram) + tokmap + tileDesc ----
__global__ __launch_bounds__(1024) void k_slots(const int* __restrict__ pidTok,
                                                int* __restrict__ tokmap,
                                                int4* __restrict__ tileDesc) {
    __shared__ int hist[NPAIR], base[NPAIR], cur[NPAIR];
    int tid = threadIdx.x;
    if (tid < NPAIR) { hist[tid] = 0; cur[tid] = 0; }
    __syncthreads();
    for (int i = tid; i < NTOK; i += 1024) atomicAdd(&hist[pidTok[i]], 1);
    __syncthreads();
    if (tid == 0) {
        int off = 0;
        for (int p = 0; p < NPAIR; ++p) { base[p] = off; off += hist[p]; }
    }
    __syncthreads();
    for (int i = tid; i < NTOK; i += 1024) {
        int p = pidTok[i];
        int pos = atomicAdd(&cur[p], 1);
        tokmap[base[p] + pos] = i;
    }
    __syncthreads();
    for (int s = tid; s < MAXT16; s += 1024) {
        int4 d; d.x = -1; d.y = 0; d.z = 0; d.w = 0;
        int toff = 0, soff = 0;
        for (int q = 0; q < NPAIR; ++q) {
            int c = hist[q];
            int nt = (c + 15) >> 4;
            if (d.x < 0 && s < toff + nt) {
                int lt = s - toff;
                d.x = q;
                d.y = soff + lt * 16;
                d.z = min(16, c - lt * 16);
            }
            toff += nt; soff += c;
        }
        tileDesc[s] = d;
    }
}

// ---- K3: gather x -> xg3[j][slot][i] bf16 (64-B rows), LDS transpose ----
__global__ __launch_bounds__(256) void k_xg3(const float* __restrict__ x,
                                             const int* __restrict__ tokmap,
                                             unsigned short* __restrict__ xg3) {
    __shared__ float tile[8][1056];                 // pad +1 per 32
    int s0 = blockIdx.x * 8;
    int tid = threadIdx.x;
    int r = tid >> 5, c = tid & 31;
    int tok = tokmap[s0 + r];
    const float* xr = x + (size_t)tok * DIM;
    #pragma unroll
    for (int u = 0; u < 8; ++u) {
        int d = u * 128 + c * 4;
        float4 v = *(const float4*)&xr[d];
        int d2 = d + (d >> 5);
        tile[r][d2 + 0] = v.x; tile[r][d2 + 1] = v.y;
        tile[r][d2 + 2] = v.z; tile[r][d2 + 3] = v.w;
    }
    __syncthreads();
    int sl = tid >> 5, j = tid & 31;
    float v[32];
    #pragma unroll
    for (int i = 0; i < 32; ++i) v[i] = tile[sl][i * 33 + j];
    unsigned short* orow = xg3 + ((size_t)j * NTOK + s0 + sl) * 32;
    #pragma unroll
    for (int ic = 0; ic < 4; ++ic) {
        uint4 pk;
        pk.x = (uint32_t)f2bf(v[ic * 8 + 0]) | ((uint32_t)f2bf(v[ic * 8 + 1]) << 16);
        pk.y = (uint32_t)f2bf(v[ic * 8 + 2]) | ((uint32_t)f2bf(v[ic * 8 + 3]) << 16);
        pk.z = (uint32_t)f2bf(v[ic * 8 + 4]) | ((uint32_t)f2bf(v[ic * 8 + 5]) << 16);
        pk.w = (uint32_t)f2bf(v[ic * 8 + 6]) | ((uint32_t)f2bf(v[ic * 8 + 7]) << 16);
        *(uint4*)(orow + ic * 8) = pk;
    }
}

// ---- K4: fused BTT — k-quarter split, plain stores, LDS-only barriers ----
__global__ __launch_bounds__(256, 3) void k_fz(const unsigned short* __restrict__ w1m,
                                               const unsigned short* __restrict__ w2m,
                                               const unsigned short* __restrict__ xg3,
                                               const float* __restrict__ bias,
                                               const int* __restrict__ tokmap,
                                               const float* __restrict__ wgt,
                                               const int4* __restrict__ tileDesc,
                                               float* __restrict__ out) {
    __shared__ unsigned short zls[8][2][4][16][8];  // 16 KB: [kk][e][joct][tslot][jj]
    __shared__ float ybuf[8192];                    // 32 KB: [t][128 quads][4], quad-swizzled

    int bid = blockIdx.x;
    int4 td = tileDesc[bid >> 2];
    int kb0 = (bid & 3) * 2;
    int p = td.x, s0 = td.y, cnt = td.z;
    if (p < 0) return;

    int a0 = 0, r0 = p;
    while (r0 >= 7 - a0) { r0 -= 7 - a0; ++a0; }
    int ea = a0, eb = a0 + 1 + r0;

    int tid = threadIdx.x;
    int w = tid >> 6, l = tid & 63;
    int lr = l & 15, lg = l >> 4;
    int e_lane = lr >> 3, kk = lr & 7;
    int my_e = e_lane ? eb : ea;

    float gs[4];
    #pragma unroll
    for (int r = 0; r < 4; ++r) {
        int tok = tokmap[min(s0 + lg * 4 + r, NTOK - 1)];
        float2 wv = *(const float2*)&wgt[tok * 2];
        gs[r] = e_lane ? wv.y : wv.x;
    }
    int tok4[4];
    #pragma unroll
    for (int tt = 0; tt < 4; ++tt)
        tok4[tt] = tokmap[min(s0 + w * 4 + tt, NTOK - 1)];

    bf16x8 a[8];
    int srow = min(s0 + lr, NTOK - 1);
    #pragma unroll
    for (int jj = 0; jj < 8; ++jj) {
        int j = w * 8 + jj;
        a[jj] = *(const bf16x8*)(xg3 + ((size_t)j * NTOK + srow) * 32 + lg * 8);
    }

    const f32x4 zero4 = {0.f, 0.f, 0.f, 0.f};
    const unsigned short* w1base = w1m + (((size_t)(my_e * 32 + w * 8) * 64) + kk) * 32 + lg * 8;

    bf16x8 w1f[8];
    #pragma unroll
    for (int jj = 0; jj < 8; ++jj)
        w1f[jj] = *(const bf16x8*)(w1base + (size_t)jj * 2048 + (size_t)kb0 * 256);

    auto phase1 = [&](int n) {
        f32x4 dj[8];
        #pragma unroll
        for (int jj = 0; jj < 8; ++jj)
            dj[jj] = __builtin_amdgcn_mfma_f32_16x16x32_bf16(a[jj], w1f[jj], zero4, 0, 0, 0);
        if (n + 1 < 2) {
            #pragma unroll
            for (int jj = 0; jj < 8; ++jj)
                w1f[jj] = *(const bf16x8*)(w1base + (size_t)jj * 2048 + (size_t)(kb0 + n + 1) * 256);
        }
        #pragma unroll
        for (int r = 0; r < 4; ++r) {
            float g = gs[r];
            int ts = (lg * 4 + r) ^ kk;
            uint4 pk;
            pk.x = (uint32_t)f2bf(dj[0][r] * g) | ((uint32_t)f2bf(dj[1][r] * g) << 16);
            pk.y = (uint32_t)f2bf(dj[2][r] * g) | ((uint32_t)f2bf(dj[3][r] * g) << 16);
            pk.z = (uint32_t)f2bf(dj[4][r] * g) | ((uint32_t)f2bf(dj[5][r] * g) << 16);
            pk.w = (uint32_t)f2bf(dj[6][r] * g) | ((uint32_t)f2bf(dj[7][r] * g) << 16);
            *(uint4*)&zls[kk][e_lane][w][ts][0] = pk;
        }
    };

    phase1(0);
    barrier_lds();

    for (int kbl = 0; kbl < 2; ++kbl) {
        int kb = kb0 + kbl;

        // ---- phase 2: A = W2 (m=l), B = z (n=token); D -> ybuf quads ----
        #pragma unroll
        for (int k = 0; k < 8; ++k) {
            int kg = kb * 8 + k;
            bf16x8 az0 = *(const bf16x8*)&zls[k][0][lg][lr ^ k][0];
            bf16x8 az1 = *(const bf16x8*)&zls[k][1][lg][lr ^ k][0];
            bf16x8 b0 = *(const bf16x8*)(w2m + (((size_t)ea * 64 + kg) * 64 + w * 16 + lr) * 32 + lg * 8);
            bf16x8 b1 = *(const bf16x8*)(w2m + (((size_t)eb * 64 + kg) * 64 + w * 16 + lr) * 32 + lg * 8);
            f32x4 acc = __builtin_amdgcn_mfma_f32_16x16x32_bf16(b0, az0, zero4, 0, 0, 0);
            acc = __builtin_amdgcn_mfma_f32_16x16x32_bf16(b1, az1, acc, 0, 0, 0);
            // lane: token=lr, l' = w*16+lg*4; logical quad = k*16 + w*4 + lg
            int pq = (k * 16 + w * 4 + lg) ^ (k & 1) ^ (lr & 7);
            *(f32x4*)&ybuf[lr * 512 + pq * 4] = acc;
        }
        barrier_lds();                              // ybuf ready; zls consumed (DS only)

        if (kbl < 1) phase1(kbl + 1);               // refill zls ∥ epilogue below

        // ---- epilogue: wave-uniform token, full-line contiguous PLAIN stores ----
        {
            f32x4 bv0 = *(const f32x4*)&bias[kb * 512 + l * 8];
            f32x4 bv1 = *(const f32x4*)&bias[kb * 512 + l * 8 + 4];
            int kq = l >> 3;
            int rbase = kq * 16 + (l & 7) * 2;
            #pragma unroll
            for (int tt = 0; tt < 4; ++tt) {
                int t = w * 4 + tt;
                if (t < cnt) {
                    int c = (kq & 1) ^ (t & 7);
                    f32x4 y0 = *(const f32x4*)&ybuf[t * 512 + ((rbase) ^ c) * 4];
                    f32x4 y1 = *(const f32x4*)&ybuf[t * 512 + ((rbase + 1) ^ c) * 4];
                    f32x4 o0 = y0 + bv0;
                    f32x4 o1 = y1 + bv1;
                    float* dst = out + (size_t)tok4[tt] * OUTD + kb * 512 + l * 8;
                    *(f32x4*)dst = o0;
                    *(f32x4*)(dst + 4) = o1;
                }
            }
        }
        if (kbl < 1) barrier_lds();                 // zls(new) ready; ybuf free (DS only)
    }
}

extern "C" void kernel_launch(void* const* d_in, const int* in_sizes, int n_in,
                              void* d_out, int out_size, void* d_ws, size_t ws_size,
                              hipStream_t stream) {
    const float* x  = (const float*)d_in[0];
    const float* Wg = (const float*)d_in[1];
    const float* W1 = (const float*)d_in[2];
    const float* W2 = (const float*)d_in[3];
    const float* b  = (const float*)d_in[4];
    float* out = (float*)d_out;

    unsigned short* w1m = (unsigned short*)d_ws;            // 1 MB
    unsigned short* w2m = w1m + 524288;                     // 2 MB
    unsigned short* xg3 = w2m + 1048576;                    // 16 MB
    int*   tokmap   = (int*)(xg3 + 8388608);                // 8192 i
    float* wgt      = (float*)(tokmap + NTOK);              // 16384 f
    int4*  tileDesc = (int4*)(wgt + 2 * NTOK);              // 539 int4
    int*   pidTok   = (int*)(tileDesc + MAXT16);            // 8192 i

    k_prep <<<416,  256, 0, stream>>>(x, Wg, W1, W2, w1m, w2m, pidTok, wgt);
    k_slots<<<1,   1024, 0, stream>>>(pidTok, tokmap, tileDesc);
    k_xg3  <<<1024, 256, 0, stream>>>(x, tokmap, xg3);
    k_fz   <<<MAXT16 * 4, 256, 0, stream>>>(w1m, w2m, xg3, b, tokmap, wgt, tileDesc, out);
}

// Round 17
// 94.277 us; speedup vs baseline: 1.7450x; 1.0425x over previous
//
#include <hip/hip_runtime.h>
#include <stdint.h>

#define NTOK 8192
#define DIM  1024
#define NE   8
#define NPAIR 28
#define OUTD 4096
#define MAXT16 539   // >= sum_p ceil(cnt_p/16): 512 + 27 worst case

typedef __attribute__((ext_vector_type(8))) short bf16x8;
typedef __attribute__((ext_vector_type(4))) float f32x4;

static __device__ __forceinline__ unsigned short f2bf(float f) {
    uint32_t u = __float_as_uint(f);
    u += 0x7fffu + ((u >> 16) & 1u);     // RNE
    return (unsigned short)(u >> 16);
}

// LDS-only barrier: wait DS ops, NOT vmcnt (stores/loads in flight stay in flight).
static __device__ __forceinline__ void barrier_lds() {
    asm volatile("s_waitcnt lgkmcnt(0)\n\ts_barrier" ::: "memory");
}

// ---- K1: fused prep. bids 0..31: W1 repack | 32..159: W2 repack | 160..415: gate (32 tok) ----
// w1m[e][j][k][i]  i contiguous : 524288 elems
// w2m[e][k][l][j]  j contiguous : 1048576 elems
__global__ __launch_bounds__(256) void k_prep(const float* __restrict__ x,
                                              const float* __restrict__ Wg,
                                              const float* __restrict__ W1,
                                              const float* __restrict__ W2,
                                              unsigned short* __restrict__ w1m,
                                              unsigned short* __restrict__ w2m,
                                              int* __restrict__ pidTok,
                                              float* __restrict__ wgt) {
    __shared__ float smemf[8448];                   // 33 KB union
    int bid = blockIdx.x;
    int tid = threadIdx.x;

    if (bid < 32) {
        // ================= W1 repack: block j, coalesced both sides =================
        int j = bid;
        unsigned short* lds = (unsigned short*)smemf;   // [32][514] bf16
        const float* src = W1 + (size_t)j * 16384;
        int f0 = tid * 64;
        #pragma unroll
        for (int c = 0; c < 16; ++c) {
            int f = f0 + c * 4;
            float4 v = *(const float4*)&src[f];
            int i = f >> 9, rem = f & 511;
            unsigned short* d = lds + i * 514 + rem;
            d[0] = f2bf(v.x); d[1] = f2bf(v.y); d[2] = f2bf(v.z); d[3] = f2bf(v.w);
        }
        __syncthreads();
        int e = tid >> 5, kp = tid & 31;
        #pragma unroll
        for (int dk = 0; dk < 2; ++dk) {
            int k = kp * 2 + dk;
            uint32_t q[16];
            #pragma unroll
            for (int c = 0; c < 16; ++c) {
                uint32_t lo = lds[(2 * c) * 514 + k * 8 + e];
                uint32_t hi = lds[(2 * c + 1) * 514 + k * 8 + e];
                q[c] = lo | (hi << 16);
            }
            unsigned short* dst = w1m + (((size_t)e * 32 + j) * 64 + k) * 32;
            #pragma unroll
            for (int c = 0; c < 4; ++c) {
                uint4 u; u.x = q[c*4]; u.y = q[c*4+1]; u.z = q[c*4+2]; u.w = q[c*4+3];
                *(uint4*)(dst + c * 8) = u;
            }
        }
    } else if (bid < 160) {
        // ================= W2 repack: block = 4 (e,k) pairs =================
        int ek4 = bid - 32;                         // 0..127
        unsigned short* lds = (unsigned short*)smemf;   // [4][32*66] bf16
        int sub = tid >> 6, l6 = tid & 63;
        const float* s2 = W2 + (size_t)ek4 * 8192 + sub * 2048 + l6 * 32;
        #pragma unroll
        for (int c = 0; c < 32; c += 4) {
            float4 v = *(const float4*)&s2[c];
            int f = l6 * 32 + c;
            int j = f >> 6, l = f & 63;
            unsigned short* d = lds + sub * 2112 + j * 66 + l;
            d[0] = f2bf(v.x); d[1] = f2bf(v.y); d[2] = f2bf(v.z); d[3] = f2bf(v.w);
        }
        __syncthreads();
        uint32_t q[16];
        #pragma unroll
        for (int c = 0; c < 16; ++c) {
            uint32_t lo = lds[sub * 2112 + (2 * c) * 66 + l6];
            uint32_t hi = lds[sub * 2112 + (2 * c + 1) * 66 + l6];
            q[c] = lo | (hi << 16);
        }
        unsigned short* dst = w2m + ((size_t)ek4 * 4 + sub) * 2048 + l6 * 32;
        #pragma unroll
        for (int c = 0; c < 4; ++c) {
            uint4 u; u.x = q[c*4]; u.y = q[c*4+1]; u.z = q[c*4+2]; u.w = q[c*4+3];
            *(uint4*)(dst + c * 8) = u;
        }
    } else {
        // ================= gate: 32 tokens/block, 8 per wave, NO atomics =================
        float* sWg = smemf;                         // [8][1024]
        #pragma unroll
        for (int u = 0; u < 8; ++u) {
            int idx = u * 1024 + tid * 4;
            *(float4*)&sWg[idx] = *(const float4*)&Wg[idx];
        }
        __syncthreads();
        int w = tid >> 6, lane = tid & 63;
        int tokBase = (bid - 160) * 32 + w * 8;
        for (int it = 0; it < 8; ++it) {
            int tok = tokBase + it;
            float acc[NE];
            #pragma unroll
            for (int e = 0; e < NE; ++e) acc[e] = 0.f;
            const float* xr = x + (size_t)tok * DIM;
            #pragma unroll
            for (int c = 0; c < 4; ++c) {
                float4 xv = *(const float4*)&xr[c * 256 + lane * 4];
                #pragma unroll
                for (int e = 0; e < NE; ++e) {
                    float4 wv = *(const float4*)&sWg[e * 1024 + c * 256 + lane * 4];
                    acc[e] += xv.x * wv.x + xv.y * wv.y + xv.z * wv.z + xv.w * wv.w;
                }
            }
            #pragma unroll
            for (int e = 0; e < NE; ++e)
                #pragma unroll
                for (int off = 32; off > 0; off >>= 1)
                    acc[e] += __shfl_xor(acc[e], off, 64);
            if (lane == 0) {
                int i1 = 0; float v1 = acc[0];
                for (int e = 1; e < NE; ++e) if (acc[e] > v1) { v1 = acc[e]; i1 = e; }
                int i2 = -1; float v2 = -3.4e38f;
                for (int e = 0; e < NE; ++e) { if (e == i1) continue; if (acc[e] > v2) { v2 = acc[e]; i2 = e; } }
                float ex = expf(v2 - v1);
                float s  = 1.f / (1.f + ex);
                float w1v = s + 1e-6f;
                float w2v = ex * s + 1e-6f;
                int ea = min(i1, i2), eb = max(i1, i2);
                float wa = (i1 < i2) ? w1v : w2v;
                float wb = (i1 < i2) ? w2v : w1v;
                wgt[tok * 2 + 0] = wa;
                wgt[tok * 2 + 1] = wb;
                pidTok[tok] = ea * 7 - (ea * (ea - 1)) / 2 + (eb - ea - 1);
            }
        }
    }
}

// ---- K2: single-block bucketize (LDS histogram) + tokmap + tileDesc ----
__global__ __launch_bounds__(1024) void k_slots(const int* __restrict__ pidTok,
                                                int* __restrict__ tokmap,
                                                int4* __restrict__ tileDesc) {
    __shared__ int hist[NPAIR], base[NPAIR], cur[NPAIR];
    int tid = threadIdx.x;
    if (tid < NPAIR) { hist[tid] = 0; cur[tid] = 0; }
    __syncthreads();
    for (int i = tid; i < NTOK; i += 1024) atomicAdd(&hist[pidTok[i]], 1);
    __syncthreads();
    if (tid == 0) {
        int off = 0;
        for (int p = 0; p < NPAIR; ++p) { base[p] = off; off += hist[p]; }
    }
    __syncthreads();
    for (int i = tid; i < NTOK; i += 1024) {
        int p = pidTok[i];
        int pos = atomicAdd(&cur[p], 1);
        tokmap[base[p] + pos] = i;
    }
    __syncthreads();
    for (int s = tid; s < MAXT16; s += 1024) {
        int4 d; d.x = -1; d.y = 0; d.z = 0; d.w = 0;
        int toff = 0, soff = 0;
        for (int q = 0; q < NPAIR; ++q) {
            int c = hist[q];
            int nt = (c + 15) >> 4;
            if (d.x < 0 && s < toff + nt) {
                int lt = s - toff;
                d.x = q;
                d.y = soff + lt * 16;
                d.z = min(16, c - lt * 16);
            }
            toff += nt; soff += c;
        }
        tileDesc[s] = d;
    }
}

// ---- K3: fused BTT — in-block x gather/transpose (no xg3), k-quarter split,
//          plain stores, LDS-only barriers. bid = th*32 + quarter*8 + tl:
//          tile = th*8+tl (same XCD for all 4 quarters -> x rows L2-hit). ----
__global__ __launch_bounds__(256, 3) void k_fz(const float* __restrict__ x,
                                               const unsigned short* __restrict__ w1m,
                                               const unsigned short* __restrict__ w2m,
                                               const float* __restrict__ bias,
                                               const int* __restrict__ tokmap,
                                               const float* __restrict__ wgt,
                                               const int4* __restrict__ tileDesc,
                                               float* __restrict__ out) {
    __shared__ unsigned short zls[8][2][4][16][8];  // 16 KB: [kk][e][joct][tslot][jj]
    __shared__ float ybuf[8192];                    // 32 KB: x-stage, then [t][quads]
    uint32_t* xs = (uint32_t*)ybuf;                 // stage: xs[j][t][q] u32 (i-pairs)

    int bid = blockIdx.x;
    int tile = ((bid >> 5) << 3) | (bid & 7);
    int quarter = (bid >> 3) & 3;
    if (tile >= MAXT16) return;
    int4 td = tileDesc[tile];
    int kb0 = quarter * 2;
    int p = td.x, s0 = td.y, cnt = td.z;
    if (p < 0) return;

    int a0 = 0, r0 = p;
    while (r0 >= 7 - a0) { r0 -= 7 - a0; ++a0; }
    int ea = a0, eb = a0 + 1 + r0;

    int tid = threadIdx.x;
    int w = tid >> 6, l = tid & 63;
    int lr = l & 15, lg = l >> 4;
    int e_lane = lr >> 3, kk = lr & 7;
    int my_e = e_lane ? eb : ea;

    float gs[4];
    #pragma unroll
    for (int r = 0; r < 4; ++r) {
        int tok = tokmap[min(s0 + lg * 4 + r, NTOK - 1)];
        float2 wv = *(const float2*)&wgt[tok * 2];
        gs[r] = e_lane ? wv.y : wv.x;
    }
    int tok4[4];
    #pragma unroll
    for (int tt = 0; tt < 4; ++tt)
        tok4[tt] = tokmap[min(s0 + w * 4 + tt, NTOK - 1)];

    const f32x4 zero4 = {0.f, 0.f, 0.f, 0.f};
    const unsigned short* w1base = w1m + (((size_t)(my_e * 32 + w * 8) * 64) + kk) * 32 + lg * 8;

    bf16x8 w1f[8];
    #pragma unroll
    for (int jj = 0; jj < 8; ++jj)
        w1f[jj] = *(const bf16x8*)(w1base + (size_t)jj * 2048 + (size_t)kb0 * 256);

    // ---- stage x: thread (t = tid>>4, q = tid&15) loads 64 consecutive floats
    // (i = 2q, 2q+1; all j) coalesced, packs i-pairs, ds_write_b32 (2-way = free).
    {
        int t = tid >> 4, q = tid & 15;
        int tok = tokmap[min(s0 + t, NTOK - 1)];
        const float* xr = x + (size_t)tok * DIM + q * 64;
        float4 va[16];
        #pragma unroll
        for (int c = 0; c < 16; ++c) va[c] = *(const float4*)&xr[c * 4];
        uint32_t* xrow = xs + t * 16 + q;
        #pragma unroll
        for (int j = 0; j < 32; ++j) {
            float lo = ((const float*)&va[j >> 2])[j & 3];        // i = 2q
            float hi = ((const float*)&va[8 + (j >> 2)])[j & 3];  // i = 2q+1
            xrow[j * 256] = (uint32_t)f2bf(lo) | ((uint32_t)f2bf(hi) << 16);
        }
    }
    barrier_lds();

    // a-frags from LDS: xs[j][lr][lg*4..+3] -> i = lg*8..lg*8+7 contiguous
    bf16x8 a[8];
    #pragma unroll
    for (int jj = 0; jj < 8; ++jj) {
        int j = w * 8 + jj;
        a[jj] = *(const bf16x8*)(xs + j * 256 + lr * 16 + lg * 4);
    }

    auto phase1 = [&](int n) {
        f32x4 dj[8];
        #pragma unroll
        for (int jj = 0; jj < 8; ++jj)
            dj[jj] = __builtin_amdgcn_mfma_f32_16x16x32_bf16(a[jj], w1f[jj], zero4, 0, 0, 0);
        if (n + 1 < 2) {
            #pragma unroll
            for (int jj = 0; jj < 8; ++jj)
                w1f[jj] = *(const bf16x8*)(w1base + (size_t)jj * 2048 + (size_t)(kb0 + n + 1) * 256);
        }
        #pragma unroll
        for (int r = 0; r < 4; ++r) {
            float g = gs[r];
            int ts = (lg * 4 + r) ^ kk;
            uint4 pk;
            pk.x = (uint32_t)f2bf(dj[0][r] * g) | ((uint32_t)f2bf(dj[1][r] * g) << 16);
            pk.y = (uint32_t)f2bf(dj[2][r] * g) | ((uint32_t)f2bf(dj[3][r] * g) << 16);
            pk.z = (uint32_t)f2bf(dj[4][r] * g) | ((uint32_t)f2bf(dj[5][r] * g) << 16);
            pk.w = (uint32_t)f2bf(dj[6][r] * g) | ((uint32_t)f2bf(dj[7][r] * g) << 16);
            *(uint4*)&zls[kk][e_lane][w][ts][0] = pk;
        }
    };

    phase1(0);
    barrier_lds();      // zls ready; all a[]-reads done -> ybuf reusable after this

    for (int kbl = 0; kbl < 2; ++kbl) {
        int kb = kb0 + kbl;

        // ---- phase 2: A = W2 (m=l), B = z (n=token); D -> ybuf quads ----
        #pragma unroll
        for (int k = 0; k < 8; ++k) {
            int kg = kb * 8 + k;
            bf16x8 az0 = *(const bf16x8*)&zls[k][0][lg][lr ^ k][0];
            bf16x8 az1 = *(const bf16x8*)&zls[k][1][lg][lr ^ k][0];
            bf16x8 b0 = *(const bf16x8*)(w2m + (((size_t)ea * 64 + kg) * 64 + w * 16 + lr) * 32 + lg * 8);
            bf16x8 b1 = *(const bf16x8*)(w2m + (((size_t)eb * 64 + kg) * 64 + w * 16 + lr) * 32 + lg * 8);
            f32x4 acc = __builtin_amdgcn_mfma_f32_16x16x32_bf16(b0, az0, zero4, 0, 0, 0);
            acc = __builtin_amdgcn_mfma_f32_16x16x32_bf16(b1, az1, acc, 0, 0, 0);
            // lane: token=lr, l' = w*16+lg*4; logical quad = k*16 + w*4 + lg
            int pq = (k * 16 + w * 4 + lg) ^ (k & 1) ^ (lr & 7);
            *(f32x4*)&ybuf[lr * 512 + pq * 4] = acc;
        }
        barrier_lds();                              // ybuf ready; zls consumed (DS only)

        if (kbl < 1) phase1(kbl + 1);               // refill zls ∥ epilogue below

        // ---- epilogue: wave-uniform token, full-line contiguous PLAIN stores ----
        {
            f32x4 bv0 = *(const f32x4*)&bias[kb * 512 + l * 8];
            f32x4 bv1 = *(const f32x4*)&bias[kb * 512 + l * 8 + 4];
            int kq = l >> 3;
            int rbase = kq * 16 + (l & 7) * 2;
            #pragma unroll
            for (int tt = 0; tt < 4; ++tt) {
                int t = w * 4 + tt;
                if (t < cnt) {
                    int c = (kq & 1) ^ (t & 7);
                    f32x4 y0 = *(const f32x4*)&ybuf[t * 512 + ((rbase) ^ c) * 4];
                    f32x4 y1 = *(const f32x4*)&ybuf[t * 512 + ((rbase + 1) ^ c) * 4];
                    f32x4 o0 = y0 + bv0;
                    f32x4 o1 = y1 + bv1;
                    float* dst = out + (size_t)tok4[tt] * OUTD + kb * 512 + l * 8;
                    *(f32x4*)dst = o0;
                    *(f32x4*)(dst + 4) = o1;
                }
            }
        }
        if (kbl < 1) barrier_lds();                 // zls(new) ready; ybuf free (DS only)
    }
}

extern "C" void kernel_launch(void* const* d_in, const int* in_sizes, int n_in,
                              void* d_out, int out_size, void* d_ws, size_t ws_size,
                              hipStream_t stream) {
    const float* x  = (const float*)d_in[0];
    const float* Wg = (const float*)d_in[1];
    const float* W1 = (const float*)d_in[2];
    const float* W2 = (const float*)d_in[3];
    const float* b  = (const float*)d_in[4];
    float* out = (float*)d_out;

    unsigned short* w1m = (unsigned short*)d_ws;            // 1 MB
    unsigned short* w2m = w1m + 524288;                     // 2 MB
    int*   tokmap   = (int*)(w2m + 1048576);                // 8192 i
    float* wgt      = (float*)(tokmap + NTOK);              // 16384 f
    int4*  tileDesc = (int4*)(wgt + 2 * NTOK);              // 539 int4
    int*   pidTok   = (int*)(tileDesc + MAXT16);            // 8192 i

    k_prep <<<416,  256, 0, stream>>>(x, Wg, W1, W2, w1m, w2m, pidTok, wgt);
    k_slots<<<1,   1024, 0, stream>>>(pidTok, tokmap, tileDesc);
    k_fz   <<<2176, 256, 0, stream>>>(x, w1m, w2m, b, tokmap, wgt, tileDesc, out);
}

// Round 19
// 87.702 us; speedup vs baseline: 1.8758x; 1.0750x over previous
//
#include <hip/hip_runtime.h>
#include <stdint.h>

#define NTOK 8192
#define DIM  1024
#define NE   8
#define NPAIR 28
#define OUTD 4096
#define MAXT16 539     // >= sum_p ceil(cnt_p/16): 512 + 27 worst case

typedef __attribute__((ext_vector_type(8))) short bf16x8;
typedef __attribute__((ext_vector_type(4))) float f32x4;

static __device__ __forceinline__ unsigned short f2bf(float f) {
    uint32_t u = __float_as_uint(f);
    u += 0x7fffu + ((u >> 16) & 1u);     // RNE
    return (unsigned short)(u >> 16);
}

// LDS-only barrier: wait DS ops, NOT vmcnt (stores/loads in flight stay in flight).
static __device__ __forceinline__ void barrier_lds() {
    asm volatile("s_waitcnt lgkmcnt(0)\n\ts_barrier" ::: "memory");
}

// ---- K1: fused prep. bids 0..31: W1 repack | 32..159: W2 repack | 160..671: gate (16 tok) ----
// w1m[e][j][k][i]  i contiguous : 524288 elems
// w2m[e][k][l][j]  j contiguous : 1048576 elems
__global__ __launch_bounds__(256) void k_prep(const float* __restrict__ x,
                                              const float* __restrict__ Wg,
                                              const float* __restrict__ W1,
                                              const float* __restrict__ W2,
                                              unsigned short* __restrict__ w1m,
                                              unsigned short* __restrict__ w2m,
                                              int* __restrict__ pidTok,
                                              float* __restrict__ wgt) {
    __shared__ float smemf[8448];                   // 33 KB union
    int bid = blockIdx.x;
    int tid = threadIdx.x;

    if (bid < 32) {
        // ================= W1 repack: block j, coalesced both sides =================
        int j = bid;
        unsigned short* lds = (unsigned short*)smemf;   // [32][514] bf16
        const float* src = W1 + (size_t)j * 16384;
        int f0 = tid * 64;
        #pragma unroll
        for (int c = 0; c < 16; ++c) {
            int f = f0 + c * 4;
            float4 v = *(const float4*)&src[f];
            int i = f >> 9, rem = f & 511;
            unsigned short* d = lds + i * 514 + rem;
            d[0] = f2bf(v.x); d[1] = f2bf(v.y); d[2] = f2bf(v.z); d[3] = f2bf(v.w);
        }
        __syncthreads();
        int e = tid >> 5, kp = tid & 31;
        #pragma unroll
        for (int dk = 0; dk < 2; ++dk) {
            int k = kp * 2 + dk;
            uint32_t q[16];
            #pragma unroll
            for (int c = 0; c < 16; ++c) {
                uint32_t lo = lds[(2 * c) * 514 + k * 8 + e];
                uint32_t hi = lds[(2 * c + 1) * 514 + k * 8 + e];
                q[c] = lo | (hi << 16);
            }
            unsigned short* dst = w1m + (((size_t)e * 32 + j) * 64 + k) * 32;
            #pragma unroll
            for (int c = 0; c < 4; ++c) {
                uint4 u; u.x = q[c*4]; u.y = q[c*4+1]; u.z = q[c*4+2]; u.w = q[c*4+3];
                *(uint4*)(dst + c * 8) = u;
            }
        }
    } else if (bid < 160) {
        // ================= W2 repack: block = 4 (e,k) pairs =================
        int ek4 = bid - 32;                         // 0..127
        unsigned short* lds = (unsigned short*)smemf;   // [4][32*66] bf16
        int sub = tid >> 6, l6 = tid & 63;
        const float* s2 = W2 + (size_t)ek4 * 8192 + sub * 2048 + l6 * 32;
        #pragma unroll
        for (int c = 0; c < 32; c += 4) {
            float4 v = *(const float4*)&s2[c];
            int f = l6 * 32 + c;
            int j = f >> 6, l = f & 63;
            unsigned short* d = lds + sub * 2112 + j * 66 + l;
            d[0] = f2bf(v.x); d[1] = f2bf(v.y); d[2] = f2bf(v.z); d[3] = f2bf(v.w);
        }
        __syncthreads();
        uint32_t q[16];
        #pragma unroll
        for (int c = 0; c < 16; ++c) {
            uint32_t lo = lds[sub * 2112 + (2 * c) * 66 + l6];
            uint32_t hi = lds[sub * 2112 + (2 * c + 1) * 66 + l6];
            q[c] = lo | (hi << 16);
        }
        unsigned short* dst = w2m + ((size_t)ek4 * 4 + sub) * 2048 + l6 * 32;
        #pragma unroll
        for (int c = 0; c < 4; ++c) {
            uint4 u; u.x = q[c*4]; u.y = q[c*4+1]; u.z = q[c*4+2]; u.w = q[c*4+3];
            *(uint4*)(dst + c * 8) = u;
        }
    } else {
        // ================= gate: 16 tokens/block, 4 per wave, NO atomics =================
        float* sWg = smemf;                         // [8][1024]
        #pragma unroll
        for (int u = 0; u < 8; ++u) {
            int idx = u * 1024 + tid * 4;
            *(float4*)&sWg[idx] = *(const float4*)&Wg[idx];
        }
        __syncthreads();
        int w = tid >> 6, lane = tid & 63;
        int tokBase = (bid - 160) * 16 + w * 4;
        for (int it = 0; it < 4; ++it) {
            int tok = tokBase + it;
            float acc[NE];
            #pragma unroll
            for (int e = 0; e < NE; ++e) acc[e] = 0.f;
            const float* xr = x + (size_t)tok * DIM;
            #pragma unroll
            for (int c = 0; c < 4; ++c) {
                float4 xv = *(const float4*)&xr[c * 256 + lane * 4];
                #pragma unroll
                for (int e = 0; e < NE; ++e) {
                    float4 wv = *(const float4*)&sWg[e * 1024 + c * 256 + lane * 4];
                    acc[e] += xv.x * wv.x + xv.y * wv.y + xv.z * wv.z + xv.w * wv.w;
                }
            }
            #pragma unroll
            for (int e = 0; e < NE; ++e)
                #pragma unroll
                for (int off = 32; off > 0; off >>= 1)
                    acc[e] += __shfl_xor(acc[e], off, 64);
            if (lane == 0) {
                int i1 = 0; float v1 = acc[0];
                for (int e = 1; e < NE; ++e) if (acc[e] > v1) { v1 = acc[e]; i1 = e; }
                int i2 = -1; float v2 = -3.4e38f;
                for (int e = 0; e < NE; ++e) { if (e == i1) continue; if (acc[e] > v2) { v2 = acc[e]; i2 = e; } }
                float ex = expf(v2 - v1);
                float s  = 1.f / (1.f + ex);
                float w1v = s + 1e-6f;
                float w2v = ex * s + 1e-6f;
                int ea = min(i1, i2), eb = max(i1, i2);
                float wa = (i1 < i2) ? w1v : w2v;
                float wb = (i1 < i2) ? w2v : w1v;
                wgt[tok * 2 + 0] = wa;
                wgt[tok * 2 + 1] = wb;
                pidTok[tok] = ea * 7 - (ea * (ea - 1)) / 2 + (eb - ea - 1);
            }
        }
    }
}

// ---- K2: single-block bucketize (LDS histogram) + tokmap + tileDesc ----
__global__ __launch_bounds__(1024) void k_slots(const int* __restrict__ pidTok,
                                                int* __restrict__ tokmap,
                                                int4* __restrict__ tileDesc) {
    __shared__ int hist[NPAIR], base[NPAIR], cur[NPAIR];
    int tid = threadIdx.x;
    if (tid < NPAIR) { hist[tid] = 0; cur[tid] = 0; }
    __syncthreads();
    for (int i = tid; i < NTOK; i += 1024) atomicAdd(&hist[pidTok[i]], 1);
    __syncthreads();
    if (tid == 0) {
        int off = 0;
        for (int p = 0; p < NPAIR; ++p) { base[p] = off; off += hist[p]; }
    }
    __syncthreads();
    for (int i = tid; i < NTOK; i += 1024) {
        int p = pidTok[i];
        int pos = atomicAdd(&cur[p], 1);
        tokmap[base[p] + pos] = i;
    }
    __syncthreads();
    for (int s = tid; s < MAXT16; s += 1024) {
        int4 d; d.x = -1; d.y = 0; d.z = 0; d.w = 0;
        int toff = 0, soff = 0;
        for (int q = 0; q < NPAIR; ++q) {
            int c = hist[q];
            int nt = (c + 15) >> 4;
            if (d.x < 0 && s < toff + nt) {
                int lt = s - toff;
                d.x = q;
                d.y = soff + lt * 16;
                d.z = min(16, c - lt * 16);
            }
            toff += nt; soff += c;
        }
        tileDesc[s] = d;
    }
}

// ---- K3: fused BTT — in-block x gather/transpose, k-quarter split, plain stores,
//          LDS-only barriers, x-chain issued FIRST (vmcnt FIFO). ----
__global__ __launch_bounds__(256, 3) void k_fz(const float* __restrict__ x,
                                               const unsigned short* __restrict__ w1m,
                                               const unsigned short* __restrict__ w2m,
                                               const float* __restrict__ bias,
                                               const int* __restrict__ tokmap,
                                               const float* __restrict__ wgt,
                                               const int4* __restrict__ tileDesc,
                                               float* __restrict__ out) {
    __shared__ unsigned short zls[8][2][4][16][8];  // 16 KB: [kk][e][joct][tslot][jj]
    __shared__ float ybuf[8192];                    // 32 KB: x-stage, then [t][quads]
    uint32_t* xs = (uint32_t*)ybuf;                 // stage: xs[j][t][q] u32 (i-pairs)

    int bid = blockIdx.x;
    int tile = ((bid >> 5) << 3) | (bid & 7);
    int quarter = (bid >> 3) & 3;
    if (tile >= MAXT16) return;
    int4 td = tileDesc[tile];
    int kb0 = quarter * 2;
    int p = td.x, s0 = td.y, cnt = td.z;
    if (p < 0) return;

    int tid = threadIdx.x;

    // ---- issue x-stage chain FIRST: tokmap -> 16 coalesced float4 loads ----
    int tS = tid >> 4, qS = tid & 15;
    int tokS = tokmap[min(s0 + tS, NTOK - 1)];
    const float* xr = x + (size_t)tokS * DIM + qS * 64;
    float4 va[16];
    #pragma unroll
    for (int c = 0; c < 16; ++c) va[c] = *(const float4*)&xr[c * 4];

    int a0 = 0, r0 = p;
    while (r0 >= 7 - a0) { r0 -= 7 - a0; ++a0; }
    int ea = a0, eb = a0 + 1 + r0;

    int w = tid >> 6, l = tid & 63;
    int lr = l & 15, lg = l >> 4;
    int e_lane = lr >> 3, kk = lr & 7;
    int my_e = e_lane ? eb : ea;

    // ---- issue W1 frag loads second (needed right after stage barrier) ----
    const unsigned short* w1base = w1m + (((size_t)(my_e * 32 + w * 8) * 64) + kk) * 32 + lg * 8;
    bf16x8 w1f[8];
    #pragma unroll
    for (int jj = 0; jj < 8; ++jj)
        w1f[jj] = *(const bf16x8*)(w1base + (size_t)jj * 2048 + (size_t)kb0 * 256);

    // ---- gate scales + epilogue tokens (needed latest) ----
    float gs[4];
    #pragma unroll
    for (int r = 0; r < 4; ++r) {
        int tok = tokmap[min(s0 + lg * 4 + r, NTOK - 1)];
        float2 wv = *(const float2*)&wgt[tok * 2];
        gs[r] = e_lane ? wv.y : wv.x;
    }
    int tok4[4];
    #pragma unroll
    for (int tt = 0; tt < 4; ++tt)
        tok4[tt] = tokmap[min(s0 + w * 4 + tt, NTOK - 1)];

    const f32x4 zero4 = {0.f, 0.f, 0.f, 0.f};

    // ---- pack + LDS transpose (waits only the x-chain: FIFO head) ----
    {
        uint32_t* xrow = xs + tS * 16 + qS;
        #pragma unroll
        for (int j = 0; j < 32; ++j) {
            float lo = ((const float*)&va[j >> 2])[j & 3];        // i = 2q
            float hi = ((const float*)&va[8 + (j >> 2)])[j & 3];  // i = 2q+1
            xrow[j * 256] = (uint32_t)f2bf(lo) | ((uint32_t)f2bf(hi) << 16);
        }
    }
    barrier_lds();

    // a-frags from LDS: xs[j][lr][lg*4..+3] -> i = lg*8..lg*8+7 contiguous
    bf16x8 a[8];
    #pragma unroll
    for (int jj = 0; jj < 8; ++jj) {
        int j = w * 8 + jj;
        a[jj] = *(const bf16x8*)(xs + j * 256 + lr * 16 + lg * 4);
    }

    auto phase1 = [&](int n) {
        f32x4 dj[8];
        #pragma unroll
        for (int jj = 0; jj < 8; ++jj)
            dj[jj] = __builtin_amdgcn_mfma_f32_16x16x32_bf16(a[jj], w1f[jj], zero4, 0, 0, 0);
        if (n + 1 < 2) {
            #pragma unroll
            for (int jj = 0; jj < 8; ++jj)
                w1f[jj] = *(const bf16x8*)(w1base + (size_t)jj * 2048 + (size_t)(kb0 + n + 1) * 256);
        }
        #pragma unroll
        for (int r = 0; r < 4; ++r) {
            float g = gs[r];
            int ts = (lg * 4 + r) ^ kk;
            uint4 pk;
            pk.x = (uint32_t)f2bf(dj[0][r] * g) | ((uint32_t)f2bf(dj[1][r] * g) << 16);
            pk.y = (uint32_t)f2bf(dj[2][r] * g) | ((uint32_t)f2bf(dj[3][r] * g) << 16);
            pk.z = (uint32_t)f2bf(dj[4][r] * g) | ((uint32_t)f2bf(dj[5][r] * g) << 16);
            pk.w = (uint32_t)f2bf(dj[6][r] * g) | ((uint32_t)f2bf(dj[7][r] * g) << 16);
            *(uint4*)&zls[kk][e_lane][w][ts][0] = pk;
        }
    };

    phase1(0);
    barrier_lds();      // zls ready; all a[]-reads done -> ybuf reusable after this

    for (int kbl = 0; kbl < 2; ++kbl) {
        int kb = kb0 + kbl;

        // ---- phase 2: A = W2 (m=l), B = z (n=token); D -> ybuf quads ----
        #pragma unroll
        for (int k = 0; k < 8; ++k) {
            int kg = kb * 8 + k;
            bf16x8 az0 = *(const bf16x8*)&zls[k][0][lg][lr ^ k][0];
            bf16x8 az1 = *(const bf16x8*)&zls[k][1][lg][lr ^ k][0];
            bf16x8 b0 = *(const bf16x8*)(w2m + (((size_t)ea * 64 + kg) * 64 + w * 16 + lr) * 32 + lg * 8);
            bf16x8 b1 = *(const bf16x8*)(w2m + (((size_t)eb * 64 + kg) * 64 + w * 16 + lr) * 32 + lg * 8);
            f32x4 acc = __builtin_amdgcn_mfma_f32_16x16x32_bf16(b0, az0, zero4, 0, 0, 0);
            acc = __builtin_amdgcn_mfma_f32_16x16x32_bf16(b1, az1, acc, 0, 0, 0);
            // lane: token=lr, l' = w*16+lg*4; logical quad = k*16 + w*4 + lg
            int pq = (k * 16 + w * 4 + lg) ^ (k & 1) ^ (lr & 7);
            *(f32x4*)&ybuf[lr * 512 + pq * 4] = acc;
        }
        barrier_lds();                              // ybuf ready; zls consumed (DS only)

        if (kbl < 1) phase1(kbl + 1);               // refill zls ∥ epilogue below

        // ---- epilogue: wave-uniform token, full-line contiguous PLAIN stores ----
        {
            f32x4 bv0 = *(const f32x4*)&bias[kb * 512 + l * 8];
            f32x4 bv1 = *(const f32x4*)&bias[kb * 512 + l * 8 + 4];
            int kq = l >> 3;
            int rbase = kq * 16 + (l & 7) * 2;
            #pragma unroll
            for (int tt = 0; tt < 4; ++tt) {
                int t = w * 4 + tt;
                if (t < cnt) {
                    int c = (kq & 1) ^ (t & 7);
                    f32x4 y0 = *(const f32x4*)&ybuf[t * 512 + ((rbase) ^ c) * 4];
                    f32x4 y1 = *(const f32x4*)&ybuf[t * 512 + ((rbase + 1) ^ c) * 4];
                    f32x4 o0 = y0 + bv0;
                    f32x4 o1 = y1 + bv1;
                    float* dst = out + (size_t)tok4[tt] * OUTD + kb * 512 + l * 8;
                    *(f32x4*)dst = o0;
                    *(f32x4*)(dst + 4) = o1;
                }
            }
        }
        if (kbl < 1) barrier_lds();                 // zls(new) ready; ybuf free (DS only)
    }
}

extern "C" void kernel_launch(void* const* d_in, const int* in_sizes, int n_in,
                              void* d_out, int out_size, void* d_ws, size_t ws_size,
                              hipStream_t stream) {
    const float* x  = (const float*)d_in[0];
    const float* Wg = (const float*)d_in[1];
    const float* W1 = (const float*)d_in[2];
    const float* W2 = (const float*)d_in[3];
    const float* b  = (const float*)d_in[4];
    float* out = (float*)d_out;

    unsigned short* w1m = (unsigned short*)d_ws;            // 1 MB
    unsigned short* w2m = w1m + 524288;                     // 2 MB
    int*   tokmap   = (int*)(w2m + 1048576);                // 8192 i
    float* wgt      = (float*)(tokmap + NTOK);              // 16384 f
    int4*  tileDesc = (int4*)(wgt + 2 * NTOK);              // 539 int4
    int*   pidTok   = (int*)(tileDesc + MAXT16);            // 8192 i

    k_prep <<<672,  256, 0, stream>>>(x, Wg, W1, W2, w1m, w2m, pidTok, wgt);
    k_slots<<<1,   1024, 0, stream>>>(pidTok, tokmap, tileDesc);
    k_fz   <<<2176, 256, 0, stream>>>(x, w1m, w2m, b, tokmap, wgt, tileDesc, out);
}